// Round 11
// baseline (1276.800 us; speedup 1.0000x reference)
//
#include <hip/hip_runtime.h>

typedef unsigned short u16;
typedef unsigned int u32;
typedef __attribute__((ext_vector_type(8))) short bf16x8;
typedef __attribute__((ext_vector_type(4))) float f32x4;

__device__ __forceinline__ float b2f(u16 u) { return __uint_as_float(((u32)u) << 16); }
__device__ __forceinline__ u16 f2b(float f) {
  u32 u = __float_as_uint(f);
  return (u16)((u + 0x7FFFu + ((u >> 16) & 1u)) >> 16);
}

__device__ __forceinline__ void gld_lds16(const void* g, void* l) {
  __builtin_amdgcn_global_load_lds((const __attribute__((address_space(1))) u32*)g,
                                   (__attribute__((address_space(3))) u32*)l, 16, 0, 0);
}

// ---------------- adp = softmax(relu(nv1@nv2), axis=1), bf16, row-major (v,w) ----------------
__global__ __launch_bounds__(256) void k_adp(const float* __restrict__ nv1,
                                             const float* __restrict__ nv2,
                                             u16* __restrict__ adp) {
  int v = blockIdx.x, t = threadIdx.x;
  __shared__ float red[8];
  const float* nrow = nv1 + v * 10;
  float z[4];
#pragma unroll
  for (int j = 0; j < 4; j++) {
    int w = t + j * 256;
    float s = 0.f;
#pragma unroll
    for (int a = 0; a < 10; a++) s += nrow[a] * nv2[a * 1024 + w];
    z[j] = fmaxf(s, 0.f);
  }
  float m = fmaxf(fmaxf(z[0], z[1]), fmaxf(z[2], z[3]));
  for (int off = 32; off; off >>= 1) m = fmaxf(m, __shfl_down(m, off));
  if ((t & 63) == 0) red[t >> 6] = m;
  __syncthreads();
  m = fmaxf(fmaxf(red[0], red[1]), fmaxf(red[2], red[3]));
  float e[4], s = 0.f;
#pragma unroll
  for (int j = 0; j < 4; j++) { e[j] = __expf(z[j] - m); s += e[j]; }
  for (int off = 32; off; off >>= 1) s += __shfl_down(s, off);
  if ((t & 63) == 0) red[4 + (t >> 6)] = s;
  __syncthreads();
  s = red[4] + red[5] + red[6] + red[7];
  float inv = 1.0f / s;
#pragma unroll
  for (int j = 0; j < 4; j++) adp[(long)v * 1024 + t + j * 256] = f2b(e[j] * inv);
}

// ---------------- transpose 1024x1024 bf16 ----------------
__global__ __launch_bounds__(256) void k_transpose(const u16* __restrict__ in, u16* __restrict__ out) {
  __shared__ u16 tile[64 * 65];
  int w0 = blockIdx.x * 64, v0 = blockIdx.y * 64, t = threadIdx.x;
  int c = t & 63, r4 = t >> 6;
  for (int rr = r4; rr < 64; rr += 4) tile[rr * 65 + c] = in[(long)(v0 + rr) * 1024 + w0 + c];
  __syncthreads();
  for (int rr = r4; rr < 64; rr += 4) out[(long)(w0 + rr) * 1024 + v0 + c] = tile[c * 65 + rr];
}

// ---------------- pack bcat rows: n = (v>>6)*128 + src*64 + (v&63) ----------------
__global__ __launch_bounds__(256) void k_pack(const u16* __restrict__ adpT, const u16* __restrict__ adp2T,
                                              u16* __restrict__ bcat) {
  int n = blockIdx.x;
  int g = n >> 7, rem = n & 127, src = rem >> 6, v = g * 64 + (rem & 63);
  const u16* s = (src ? adp2T : adpT) + (long)v * 1024;
  u16* d = bcat + (long)n * 1024;
  ((ushort4*)d)[threadIdx.x] = ((const ushort4*)s)[threadIdx.x];
}

// ---------------- weight repacks + summed skip bias ----------------
// fwgB[layer][n 0..63][k 0..63] bf16: n<32 -> filter oc, n>=32 -> gate oc; k = tap*32 + ci.
__global__ __launch_bounds__(256) void k_wprep(const float* __restrict__ skw, const float* __restrict__ skb,
                                               const float* __restrict__ e1w,
                                               const float* __restrict__ fw, const float* __restrict__ gw,
                                               const float* __restrict__ gcw,
                                               u16* __restrict__ wcat, u16* __restrict__ e1bf,
                                               float* __restrict__ sbias,
                                               u16* __restrict__ fwgB, u16* __restrict__ gcwB) {
  int idx = blockIdx.x * 256 + threadIdx.x;
  if (idx < 65536) {
    int cp = idx >> 8, k = idx & 255, i = k >> 5, c = k & 31;
    wcat[idx] = f2b(skw[(i * 256 + cp) * 32 + c]);
  } else if (idx < 196608) {
    int j = idx - 65536;
    e1bf[j] = f2b(e1w[j]);
  } else if (idx < 229376) {
    int j = idx - 196608;
    int layer = j >> 12, rem = j & 4095, n = rem >> 6, k = rem & 63;
    int tap = k >> 5, ci = k & 31, oc = n & 31;
    const float* src = (n < 32) ? fw : gw;
    fwgB[j] = f2b(src[((layer * 32 + oc) * 32 + ci) * 2 + tap]);
  } else if (idx < 253952) {
    int j = idx - 229376;  // native-order bf16 copy of gc_w
    gcwB[j] = f2b(gcw[j]);
  }
  if (idx < 256) {
    float s = 0.f;
    for (int i = 0; i < 8; i++) s += skb[i * 256 + idx];
    sbias[idx] = s;
  }
}

// ---------------- start conv: h[b][slot][v][c] bf16 — full-line (64B) writes per thread --------
__global__ __launch_bounds__(256) void k_start(const float* __restrict__ x, const float* __restrict__ sw,
                                               const float* __restrict__ sb, u16* __restrict__ h, int b0) {
  int bl = blockIdx.y, bg = b0 + bl, v0 = blockIdx.x * 64, t = threadIdx.x;
  __shared__ float xs[2 * 832];  // [i][vl*13+l]
  for (int idx = t; idx < 2 * 832; idx += 256) {
    int i = idx / 832, rem = idx % 832;
    xs[idx] = x[((long)(bg * 2 + i) * 1024 + v0) * 13 + rem];
  }
  __syncthreads();
  for (int p = t; p < 832; p += 256) {
    int l = p % 13, vl = p / 13;
    float x0 = xs[vl * 13 + l];
    float x1 = xs[832 + vl * 13 + l];
    u16* dst = h + ((long)(bl * 13 + l) * 1024 + v0 + vl) * 32;
#pragma unroll
    for (int cq = 0; cq < 4; cq++) {
      bf16x8 pk;
#pragma unroll
      for (int j = 0; j < 8; j++) {
        int c = cq * 8 + j;
        pk[j] = (short)f2b(sw[c * 2 + 0] * x0 + sw[c * 2 + 1] * x1 + sb[c]);
      }
      *(bf16x8*)(dst + cq * 8) = pk;
    }
  }
}

// ---------------- gated dilated conv via MFMA: M=v, N=64 (f|g), K=64 (2 taps x 32 ci) ----------
__global__ __launch_bounds__(256, 2) void k_gate(const u16* __restrict__ h, u16* __restrict__ hg,
                                                 u16* __restrict__ hlast,
                                                 const u16* __restrict__ fwgB,
                                                 const float* __restrict__ fb, const float* __restrict__ gb,
                                                 int Lo, int d, int off, int layer, int writehg) {
  int t = threadIdx.x, wave = t >> 6, lane = t & 63;
  int q = lane >> 4, r = lane & 15;
  int b = blockIdx.z, l = blockIdx.y;
  int vbase = blockIdx.x * 256 + wave * 64;
  f32x4 acc[4][4] = {};
  const u16* wb = fwgB + layer * 4096;
#pragma unroll
  for (int ks = 0; ks < 2; ks++) {
    const u16* hrow = h + ((long)(b * 13 + off + l + ks * d) * 1024) * 32;
    bf16x8 af[4], bf[4];
#pragma unroll
    for (int mt = 0; mt < 4; mt++)
      af[mt] = *(const bf16x8*)(hrow + (long)(vbase + mt * 16 + r) * 32 + q * 8);
#pragma unroll
    for (int nt = 0; nt < 4; nt++)
      bf[nt] = *(const bf16x8*)(wb + (nt * 16 + r) * 64 + ks * 32 + q * 8);
#pragma unroll
    for (int mt = 0; mt < 4; mt++)
#pragma unroll
      for (int nt = 0; nt < 4; nt++)
        acc[mt][nt] = __builtin_amdgcn_mfma_f32_16x16x32_bf16(af[mt], bf[nt], acc[mt][nt], 0, 0, 0);
  }
  int last = (l == Lo - 1);
#pragma unroll
  for (int nt = 0; nt < 2; nt++) {
    int oc = nt * 16 + r;
    float fbv = fb[layer * 32 + oc], gbv = gb[layer * 32 + oc];
#pragma unroll
    for (int mt = 0; mt < 4; mt++) {
      u16 vv[4];
#pragma unroll
      for (int rg = 0; rg < 4; rg++) {
        float f = acc[mt][nt][rg] + fbv;
        float g = acc[mt][nt + 2][rg] + gbv;
        float ft = 2.f * __builtin_amdgcn_rcpf(1.f + __expf(-2.f * f)) - 1.f;
        float sg = __builtin_amdgcn_rcpf(1.f + __expf(-g));
        vv[rg] = f2b(ft * sg);
      }
      int v0 = vbase + mt * 16 + q * 4;
      if (writehg) {
        ushort4 pk; pk.x = vv[0]; pk.y = vv[1]; pk.z = vv[2]; pk.w = vv[3];
        *(ushort4*)(hg + ((long)(b * Lo + l) * 32 + oc) * 1024 + v0) = pk;
      }
      if (last) {
#pragma unroll
        for (int rg = 0; rg < 4; rg++)
          hlast[((long)(b * 1024 + v0 + rg)) * 256 + layer * 32 + oc] = vv[rg];
      }
    }
  }
}

// ---------------- generic GEMM (m97 structure), used for adp2 + end-head ----------------
__global__ __launch_bounds__(256) void k_gemm(const u16* __restrict__ A, const u16* __restrict__ Bt,
                                              u16* __restrict__ C, int M, int N, int K,
                                              const float* __restrict__ bias, int relu) {
  __shared__ __align__(16) u16 As[128 * 32];
  __shared__ __align__(16) u16 Bs[128 * 32];
  int t = threadIdx.x, wave = t >> 6, lane = t & 63;
  int m0 = blockIdx.y * 128, n0 = blockIdx.x * 128;
  int wr = (wave >> 1) * 64, wc = (wave & 1) * 64;
  int q = lane >> 4, r = lane & 15;
  f32x4 acc[4][4] = {};
  const u16* Ag = A + (long)(m0 + wave * 32 + (lane >> 2)) * K + (lane & 3) * 8;
  const u16* Bg = Bt + (long)(n0 + wave * 32 + (lane >> 2)) * K + (lane & 3) * 8;
  u16* Al = As + wave * 1024 + lane * 8;
  u16* Bl = Bs + wave * 1024 + lane * 8;
  for (int k0 = 0; k0 < K; k0 += 32) {
    __syncthreads();
    gld_lds16(Ag + k0, Al);
    gld_lds16(Ag + 16 * K + k0, Al + 512);
    gld_lds16(Bg + k0, Bl);
    gld_lds16(Bg + 16 * K + k0, Bl + 512);
    __syncthreads();
    bf16x8 af[4], bfr[4];
#pragma unroll
    for (int i = 0; i < 4; i++) {
      af[i] = *(const bf16x8*)(As + (wr + i * 16 + r) * 32 + q * 8);
      bfr[i] = *(const bf16x8*)(Bs + (wc + i * 16 + r) * 32 + q * 8);
    }
#pragma unroll
    for (int i = 0; i < 4; i++)
#pragma unroll
      for (int j = 0; j < 4; j++)
        acc[i][j] = __builtin_amdgcn_mfma_f32_16x16x32_bf16(af[i], bfr[j], acc[i][j], 0, 0, 0);
  }
#pragma unroll
  for (int i = 0; i < 4; i++) {
    int row = m0 + wr + i * 16 + q * 4;
#pragma unroll
    for (int j = 0; j < 4; j++) {
      int col = n0 + wc + j * 16 + r;
      float bv = bias ? bias[col] : 0.f;
#pragma unroll
      for (int rg = 0; rg < 4; rg++) {
        float vv = acc[i][j][rg] + bv;
        if (relu) vv = fmaxf(vv, 0.f);
        C[(long)(row + rg) * N + col] = f2b(vv);
      }
    }
  }
}

// ---------------- FUSED: x-GEMM + gc channel-mix (mini-MFMA) + res + BN (h in v-major) ----------
// grid: x = M-blocks (fast, streams A), y = 16 n-groups (slow, B L2-resident).
// mini-gemm hg operand extracted from As in-loop (k0>>6 == g) -> no global hg re-read, no hgs LDS.
#define PAD 130
__global__ __launch_bounds__(256) void k_xgc(const u16* __restrict__ hg, const u16* __restrict__ bcat,
                                             u16* __restrict__ h,
                                             const u16* __restrict__ gcwB, const float* __restrict__ gcb,
                                             const float* __restrict__ bng, const float* __restrict__ bnb,
                                             int Lo, int d, int off, int layer) {
  __shared__ __align__(16) u16 smem[16640];  // 33.3 KB: As[0..4096) Bs[4096..8192) in loop; xcs spans all after
  u16* As = smem;
  u16* Bs = smem + 4096;
  u16* xcs = smem;           // [n 0..127][m 0..127], PAD 130 (written after loop)
  int t = threadIdx.x, wave = t >> 6, lane = t & 63;
  int m0 = blockIdx.x * 128, g = blockIdx.y, n0 = g * 128;
  int wr = (wave >> 1) * 64, wc = (wave & 1) * 64;
  int q = lane >> 4, r = lane & 15;
  const int K = 1024;
  f32x4 acc[4][4] = {};
  bf16x8 miniA[4];
  const u16* Ag = hg + (long)(m0 + wave * 32 + (lane >> 2)) * K + (lane & 3) * 8;
  const u16* Bg = bcat + (long)(n0 + wave * 32 + (lane >> 2)) * K + (lane & 3) * 8;
  u16* Al = As + wave * 1024 + lane * 8;
  u16* Bl = Bs + wave * 1024 + lane * 8;
  for (int k0 = 0; k0 < K; k0 += 32) {
    __syncthreads();
    gld_lds16(Ag + k0, Al);
    gld_lds16(Ag + 16 * K + k0, Al + 512);
    gld_lds16(Bg + k0, Bl);
    gld_lds16(Bg + 16 * K + k0, Bl + 512);
    __syncthreads();
    bf16x8 af[4], bfr[4];
#pragma unroll
    for (int i = 0; i < 4; i++) {
      af[i] = *(const bf16x8*)(As + (wr + i * 16 + r) * 32 + q * 8);
      bfr[i] = *(const bf16x8*)(Bs + (wc + i * 16 + r) * 32 + q * 8);
    }
#pragma unroll
    for (int i = 0; i < 4; i++)
#pragma unroll
      for (int j = 0; j < 4; j++)
        acc[i][j] = __builtin_amdgcn_mfma_f32_16x16x32_bf16(af[i], bfr[j], acc[i][j], 0, 0, 0);
    if ((k0 >> 6) == g) {
      // extract this wave's mini-A hg fragments from As: Amini[w=mt*16+r][c=q*8+j]
      int half = (k0 >> 5) & 1;
#pragma unroll
      for (int mtl = 0; mtl < 2; mtl++) {
        int mt = half * 2 + mtl;
        int kk = mtl * 16 + r;  // mt*16 + r - half*32
        bf16x8 a;
#pragma unroll
        for (int j = 0; j < 8; j++)
          a[j] = (short)As[(wave * 32 + q * 8 + j) * 32 + kk];
        miniA[mt] = a;
      }
    }
  }
  __syncthreads();  // all waves done with As/Bs before xcs overlay
  // acc -> xcs transposed: xcs[n_local][m_local]
#pragma unroll
  for (int i = 0; i < 4; i++) {
#pragma unroll
    for (int j = 0; j < 4; j++) {
      int row_m = wr + i * 16 + q * 4;
      int col_n = wc + j * 16 + r;
      ushort4 pk;
      pk.x = f2b(acc[i][j][0]); pk.y = f2b(acc[i][j][1]);
      pk.z = f2b(acc[i][j][2]); pk.w = f2b(acc[i][j][3]);
      *(ushort4*)(xcs + col_n * PAD + row_m) = pk;
    }
  }
  __syncthreads();
  // mini-GEMM per wave (= bl group): out[w 0..63][oc 0..31], K2=96 (hg from miniA, x1/x2 from xcs)
  int blg = blockIdx.x * 4 + wave;
  int b = blg / Lo, l = blg % Lo;
  bf16x8 bf2[2][3];
#pragma unroll
  for (int nt = 0; nt < 2; nt++)
#pragma unroll
    for (int ks = 0; ks < 3; ks++)
      bf2[nt][ks] = *(const bf16x8*)(gcwB + ((long)layer * 32 + nt * 16 + r) * 96 + ks * 32 + q * 8);
  f32x4 acc2[4][2] = {};
#pragma unroll
  for (int mt = 0; mt < 4; mt++) {
#pragma unroll
    for (int nt = 0; nt < 2; nt++)
      acc2[mt][nt] = __builtin_amdgcn_mfma_f32_16x16x32_bf16(miniA[mt], bf2[nt][0], acc2[mt][nt], 0, 0, 0);
#pragma unroll
    for (int ks = 1; ks < 3; ks++) {
      bf16x8 a2 = *(const bf16x8*)(xcs + ((ks - 1) * 64 + mt * 16 + r) * PAD + wave * 32 + q * 8);
#pragma unroll
      for (int nt = 0; nt < 2; nt++)
        acc2[mt][nt] = __builtin_amdgcn_mfma_f32_16x16x32_bf16(a2, bf2[nt][ks], acc2[mt][nt], 0, 0, 0);
    }
  }
  // epilogue: + gcb, residual, BN, in-place h write (v-major layout).
  const float rs = rsqrtf(1.f + 1e-5f);
  u16* hbase = h + ((long)(b * 13 + off + l + d) * 1024 + g * 64) * 32;
#pragma unroll
  for (int nt = 0; nt < 2; nt++) {
    int oc = nt * 16 + r;
    float gbv = gcb[layer * 32 + oc];
    float sc = bng[layer * 32 + oc] * rs;
    float bb = bnb[layer * 32 + oc];
#pragma unroll
    for (int mt = 0; mt < 4; mt++) {
#pragma unroll
      for (int rg = 0; rg < 4; rg++) {
        int w = mt * 16 + q * 4 + rg;
        u16* hp = hbase + (long)w * 32 + oc;
        float res = b2f(*hp);
        *hp = f2b((acc2[mt][nt][rg] + gbv + res) * sc + bb);
      }
    }
  }
}

// ---------------- final 12-wide conv, split-K x4 + LDS reduce: out fp32 ----------------
__global__ __launch_bounds__(256) void k_e3(const u16* __restrict__ e1, const float* __restrict__ w2,
                                            const float* __restrict__ b2, float* __restrict__ out, int b0) {
  __shared__ float red[256 * 13];
  int t = threadIdx.x;
  int r = t & 63, qq = t >> 6;
  long rowi = (long)blockIdx.x * 64 + r;
  const u16* rp = e1 + rowi * 512 + qq * 128;
  float acc[12];
#pragma unroll
  for (int o = 0; o < 12; o++) acc[o] = 0.f;
  for (int ec = 0; ec < 128; ec += 8) {
    bf16x8 raw = *(const bf16x8*)(rp + ec);
    float xv[8];
#pragma unroll
    for (int jj = 0; jj < 8; jj++) xv[jj] = b2f((u16)raw[jj]);
#pragma unroll
    for (int o = 0; o < 12; o++) {
      const float* w = w2 + o * 512 + qq * 128 + ec;
#pragma unroll
      for (int jj = 0; jj < 8; jj++) acc[o] += w[jj] * xv[jj];
    }
  }
#pragma unroll
  for (int o = 0; o < 12; o++) red[t * 13 + o] = acc[o];
  __syncthreads();
  if (t < 64) {
    long row = (long)blockIdx.x * 64 + t;
    int b = b0 + (int)(row >> 10), v = (int)(row & 1023);
#pragma unroll
    for (int o = 0; o < 12; o++) {
      float s = red[t * 13 + o] + red[(64 + t) * 13 + o] + red[(128 + t) * 13 + o] + red[(192 + t) * 13 + o];
      out[((long)b * 12 + o) * 1024 + v] = s + b2[o];
    }
  }
}

extern "C" void kernel_launch(void* const* d_in, const int* in_sizes, int n_in,
                              void* d_out, int out_size, void* d_ws, size_t ws_size,
                              hipStream_t stream) {
  const float* x = (const float*)d_in[0];
  const float* start_w = (const float*)d_in[1];
  const float* start_b = (const float*)d_in[2];
  const float* nv1 = (const float*)d_in[3];
  const float* nv2 = (const float*)d_in[4];
  const float* filter_w = (const float*)d_in[5];
  const float* filter_b = (const float*)d_in[6];
  const float* gate_w = (const float*)d_in[7];
  const float* gate_b = (const float*)d_in[8];
  const float* skip_w = (const float*)d_in[9];
  const float* skip_b = (const float*)d_in[10];
  const float* gc_w = (const float*)d_in[11];
  const float* gc_b = (const float*)d_in[12];
  const float* bn_g = (const float*)d_in[13];
  const float* bn_b = (const float*)d_in[14];
  const float* end1_w = (const float*)d_in[15];
  const float* end1_b = (const float*)d_in[16];
  const float* end2_w = (const float*)d_in[17];
  const float* end2_b = (const float*)d_in[18];
  float* out = (float*)d_out;

  char* ws = (char*)d_ws;
  // ---- fixed region ----
  u16* adp = (u16*)(ws + 0);                  //  2,097,152
  u16* bcat = (u16*)(ws + 2097152ull);        //  4,194,304 (reordered rows)
  u16* wcat = (u16*)(ws + 6291456ull);        //    131,072
  u16* e1bf = (u16*)(ws + 6422528ull);        //    262,144
  float* sbias = (float*)(ws + 6684672ull);   //      1,024
  u16* fwgB = (u16*)(ws + 6685696ull);        //     65,536
  u16* gcwB = (u16*)(ws + 6751232ull);        //     49,152
  const size_t o_dyn = 6800384ull;

  // ---- adaptive batch chunking: per-batch dyn = 2,162,688 B (h+hg+hlast) ----
  int BCH = 16;
  {
    const int cand[5] = {64, 48, 32, 24, 16};
    for (int ci = 0; ci < 5; ci++) {
      size_t need = o_dyn + (size_t)cand[ci] * 2162688ull;
      if (need <= ws_size) { BCH = cand[ci]; break; }
    }
  }
  u16* h = (u16*)(ws + o_dyn);                                 // BCH*851,968  (b,13,v,c)
  u16* hg = (u16*)(ws + o_dyn + (size_t)BCH * 851968ull);      // BCH*786,432  (b,l,c,v)
  u16* hlast = (u16*)(ws + o_dyn + (size_t)BCH * 1638400ull);  // BCH*524,288
  // pre-loop temps (in h region, dead before k_start):
  u16* adpT_p = (u16*)(ws + o_dyn);
  u16* adp2T_p = (u16*)(ws + o_dyn + 2097152ull);
  // end-phase aliases (h/hg dead then)
  u16* e1c = (u16*)(ws + o_dyn);
  u16* srelu = (u16*)(ws + o_dyn + (size_t)BCH * 1048576ull);

  static const int dilA[8] = {1, 2, 1, 2, 1, 2, 1, 2};
  static const int offA[8] = {0, 1, 3, 4, 6, 7, 9, 10};

  k_wprep<<<992, 256, 0, stream>>>(skip_w, skip_b, end1_w, filter_w, gate_w, gc_w,
                                   wcat, e1bf, sbias, fwgB, gcwB);
  k_adp<<<1024, 256, 0, stream>>>(nv1, nv2, adp);
  k_transpose<<<dim3(16, 16), 256, 0, stream>>>(adp, adpT_p);
  k_gemm<<<dim3(8, 8), 256, 0, stream>>>(adpT_p, adp, adp2T_p, 1024, 1024, 1024, nullptr, 0);
  k_pack<<<2048, 256, 0, stream>>>(adpT_p, adp2T_p, bcat);

  for (int b0 = 0; b0 < 64; b0 += BCH) {
    int bc = (64 - b0 < BCH) ? (64 - b0) : BCH;
    k_start<<<dim3(16, bc), 256, 0, stream>>>(x, start_w, start_b, h, b0);
    for (int i = 0; i < 8; i++) {
      int d = dilA[i], off = offA[i], Lo = 13 - off - d;
      k_gate<<<dim3(4, Lo, bc), 256, 0, stream>>>(h, hg, hlast, fwgB, filter_b, gate_b,
                                                  Lo, d, off, i, (i < 7) ? 1 : 0);
      if (i < 7) {
        k_xgc<<<dim3(bc * Lo / 4, 16), 256, 0, stream>>>(hg, bcat, h, gcwB, gc_b,
                                                         bn_g, bn_b, Lo, d, off, i);
      }
    }
    int Mc = bc * 1024;
    k_gemm<<<dim3(2, Mc / 128), 256, 0, stream>>>(hlast, wcat, srelu, Mc, 256, 256, sbias, 1);
    k_gemm<<<dim3(4, Mc / 128), 256, 0, stream>>>(srelu, e1bf, e1c, Mc, 512, 256, end1_b, 1);
    k_e3<<<bc * 16, 256, 0, stream>>>(e1c, end2_w, end2_b, out, b0);
  }
  (void)in_sizes; (void)n_in; (void)out_size;
}

// Round 12
// 1152.272 us; speedup vs baseline: 1.1081x; 1.1081x over previous
//
#include <hip/hip_runtime.h>

typedef unsigned short u16;
typedef unsigned int u32;
typedef __attribute__((ext_vector_type(8))) short bf16x8;
typedef __attribute__((ext_vector_type(4))) float f32x4;

__device__ __forceinline__ float b2f(u16 u) { return __uint_as_float(((u32)u) << 16); }
__device__ __forceinline__ u16 f2b(float f) {
  u32 u = __float_as_uint(f);
  return (u16)((u + 0x7FFFu + ((u >> 16) & 1u)) >> 16);
}

__device__ __forceinline__ void gld_lds16(const void* g, void* l) {
  __builtin_amdgcn_global_load_lds((const __attribute__((address_space(1))) u32*)g,
                                   (__attribute__((address_space(3))) u32*)l, 16, 0, 0);
}

// ---------------- adp = softmax(relu(nv1@nv2), axis=1), bf16, row-major (v,w) ----------------
__global__ __launch_bounds__(256) void k_adp(const float* __restrict__ nv1,
                                             const float* __restrict__ nv2,
                                             u16* __restrict__ adp) {
  int v = blockIdx.x, t = threadIdx.x;
  __shared__ float red[8];
  const float* nrow = nv1 + v * 10;
  float z[4];
#pragma unroll
  for (int j = 0; j < 4; j++) {
    int w = t + j * 256;
    float s = 0.f;
#pragma unroll
    for (int a = 0; a < 10; a++) s += nrow[a] * nv2[a * 1024 + w];
    z[j] = fmaxf(s, 0.f);
  }
  float m = fmaxf(fmaxf(z[0], z[1]), fmaxf(z[2], z[3]));
  for (int off = 32; off; off >>= 1) m = fmaxf(m, __shfl_down(m, off));
  if ((t & 63) == 0) red[t >> 6] = m;
  __syncthreads();
  m = fmaxf(fmaxf(red[0], red[1]), fmaxf(red[2], red[3]));
  float e[4], s = 0.f;
#pragma unroll
  for (int j = 0; j < 4; j++) { e[j] = __expf(z[j] - m); s += e[j]; }
  for (int off = 32; off; off >>= 1) s += __shfl_down(s, off);
  if ((t & 63) == 0) red[4 + (t >> 6)] = s;
  __syncthreads();
  s = red[4] + red[5] + red[6] + red[7];
  float inv = 1.0f / s;
#pragma unroll
  for (int j = 0; j < 4; j++) adp[(long)v * 1024 + t + j * 256] = f2b(e[j] * inv);
}

// ---------------- transpose 1024x1024 bf16 ----------------
__global__ __launch_bounds__(256) void k_transpose(const u16* __restrict__ in, u16* __restrict__ out) {
  __shared__ u16 tile[64 * 65];
  int w0 = blockIdx.x * 64, v0 = blockIdx.y * 64, t = threadIdx.x;
  int c = t & 63, r4 = t >> 6;
  for (int rr = r4; rr < 64; rr += 4) tile[rr * 65 + c] = in[(long)(v0 + rr) * 1024 + w0 + c];
  __syncthreads();
  for (int rr = r4; rr < 64; rr += 4) out[(long)(w0 + rr) * 1024 + v0 + c] = tile[c * 65 + rr];
}

// ---------------- pack bcat rows: n = (v>>6)*128 + src*64 + (v&63) ----------------
__global__ __launch_bounds__(256) void k_pack(const u16* __restrict__ adpT, const u16* __restrict__ adp2T,
                                              u16* __restrict__ bcat) {
  int n = blockIdx.x;
  int g = n >> 7, rem = n & 127, src = rem >> 6, v = g * 64 + (rem & 63);
  const u16* s = (src ? adp2T : adpT) + (long)v * 1024;
  u16* d = bcat + (long)n * 1024;
  ((ushort4*)d)[threadIdx.x] = ((const ushort4*)s)[threadIdx.x];
}

// ---------------- weight repacks + summed skip bias ----------------
// fwgB[layer][n 0..63][k 0..63] bf16: n<32 -> filter oc, n>=32 -> gate oc; k = tap*32 + ci.
__global__ __launch_bounds__(256) void k_wprep(const float* __restrict__ skw, const float* __restrict__ skb,
                                               const float* __restrict__ e1w,
                                               const float* __restrict__ fw, const float* __restrict__ gw,
                                               const float* __restrict__ gcw,
                                               u16* __restrict__ wcat, u16* __restrict__ e1bf,
                                               float* __restrict__ sbias,
                                               u16* __restrict__ fwgB, u16* __restrict__ gcwB) {
  int idx = blockIdx.x * 256 + threadIdx.x;
  if (idx < 65536) {
    int cp = idx >> 8, k = idx & 255, i = k >> 5, c = k & 31;
    wcat[idx] = f2b(skw[(i * 256 + cp) * 32 + c]);
  } else if (idx < 196608) {
    int j = idx - 65536;
    e1bf[j] = f2b(e1w[j]);
  } else if (idx < 229376) {
    int j = idx - 196608;
    int layer = j >> 12, rem = j & 4095, n = rem >> 6, k = rem & 63;
    int tap = k >> 5, ci = k & 31, oc = n & 31;
    const float* src = (n < 32) ? fw : gw;
    fwgB[j] = f2b(src[((layer * 32 + oc) * 32 + ci) * 2 + tap]);
  } else if (idx < 253952) {
    int j = idx - 229376;  // native-order bf16 copy of gc_w
    gcwB[j] = f2b(gcw[j]);
  }
  if (idx < 256) {
    float s = 0.f;
    for (int i = 0; i < 8; i++) s += skb[i * 256 + idx];
    sbias[idx] = s;
  }
}

// ---------------- start conv: h[b][slot][v][c] bf16 — full-line (64B) writes per thread --------
__global__ __launch_bounds__(256) void k_start(const float* __restrict__ x, const float* __restrict__ sw,
                                               const float* __restrict__ sb, u16* __restrict__ h, int b0) {
  int bl = blockIdx.y, bg = b0 + bl, v0 = blockIdx.x * 64, t = threadIdx.x;
  __shared__ float xs[2 * 832];  // [i][vl*13+l]
  for (int idx = t; idx < 2 * 832; idx += 256) {
    int i = idx / 832, rem = idx % 832;
    xs[idx] = x[((long)(bg * 2 + i) * 1024 + v0) * 13 + rem];
  }
  __syncthreads();
  for (int p = t; p < 832; p += 256) {
    int l = p % 13, vl = p / 13;
    float x0 = xs[vl * 13 + l];
    float x1 = xs[832 + vl * 13 + l];
    u16* dst = h + ((long)(bl * 13 + l) * 1024 + v0 + vl) * 32;
#pragma unroll
    for (int cq = 0; cq < 4; cq++) {
      bf16x8 pk;
#pragma unroll
      for (int j = 0; j < 8; j++) {
        int c = cq * 8 + j;
        pk[j] = (short)f2b(sw[c * 2 + 0] * x0 + sw[c * 2 + 1] * x1 + sb[c]);
      }
      *(bf16x8*)(dst + cq * 8) = pk;
    }
  }
}

// ---------------- gated dilated conv via MFMA: M=v, N=64 (f|g), K=64 (2 taps x 32 ci) ----------
__global__ __launch_bounds__(256, 2) void k_gate(const u16* __restrict__ h, u16* __restrict__ hg,
                                                 u16* __restrict__ hlast,
                                                 const u16* __restrict__ fwgB,
                                                 const float* __restrict__ fb, const float* __restrict__ gb,
                                                 int Lo, int d, int off, int layer, int writehg) {
  int t = threadIdx.x, wave = t >> 6, lane = t & 63;
  int q = lane >> 4, r = lane & 15;
  int b = blockIdx.z, l = blockIdx.y;
  int vbase = blockIdx.x * 256 + wave * 64;
  f32x4 acc[4][4] = {};
  const u16* wb = fwgB + layer * 4096;
#pragma unroll
  for (int ks = 0; ks < 2; ks++) {
    const u16* hrow = h + ((long)(b * 13 + off + l + ks * d) * 1024) * 32;
    bf16x8 af[4], bf[4];
#pragma unroll
    for (int mt = 0; mt < 4; mt++)
      af[mt] = *(const bf16x8*)(hrow + (long)(vbase + mt * 16 + r) * 32 + q * 8);
#pragma unroll
    for (int nt = 0; nt < 4; nt++)
      bf[nt] = *(const bf16x8*)(wb + (nt * 16 + r) * 64 + ks * 32 + q * 8);
#pragma unroll
    for (int mt = 0; mt < 4; mt++)
#pragma unroll
      for (int nt = 0; nt < 4; nt++)
        acc[mt][nt] = __builtin_amdgcn_mfma_f32_16x16x32_bf16(af[mt], bf[nt], acc[mt][nt], 0, 0, 0);
  }
  int last = (l == Lo - 1);
#pragma unroll
  for (int nt = 0; nt < 2; nt++) {
    int oc = nt * 16 + r;
    float fbv = fb[layer * 32 + oc], gbv = gb[layer * 32 + oc];
#pragma unroll
    for (int mt = 0; mt < 4; mt++) {
      u16 vv[4];
#pragma unroll
      for (int rg = 0; rg < 4; rg++) {
        float f = acc[mt][nt][rg] + fbv;
        float g = acc[mt][nt + 2][rg] + gbv;
        float ft = 2.f * __builtin_amdgcn_rcpf(1.f + __expf(-2.f * f)) - 1.f;
        float sg = __builtin_amdgcn_rcpf(1.f + __expf(-g));
        vv[rg] = f2b(ft * sg);
      }
      int v0 = vbase + mt * 16 + q * 4;
      if (writehg) {
        ushort4 pk; pk.x = vv[0]; pk.y = vv[1]; pk.z = vv[2]; pk.w = vv[3];
        *(ushort4*)(hg + ((long)(b * Lo + l) * 32 + oc) * 1024 + v0) = pk;
      }
      if (last) {
#pragma unroll
        for (int rg = 0; rg < 4; rg++)
          hlast[((long)(b * 1024 + v0 + rg)) * 256 + layer * 32 + oc] = vv[rg];
      }
    }
  }
}

// ---------------- generic GEMM (m97 structure), used for adp2 + end-head ----------------
__global__ __launch_bounds__(256) void k_gemm(const u16* __restrict__ A, const u16* __restrict__ Bt,
                                              u16* __restrict__ C, int M, int N, int K,
                                              const float* __restrict__ bias, int relu) {
  __shared__ __align__(16) u16 As[128 * 32];
  __shared__ __align__(16) u16 Bs[128 * 32];
  int t = threadIdx.x, wave = t >> 6, lane = t & 63;
  int m0 = blockIdx.y * 128, n0 = blockIdx.x * 128;
  int wr = (wave >> 1) * 64, wc = (wave & 1) * 64;
  int q = lane >> 4, r = lane & 15;
  f32x4 acc[4][4] = {};
  const u16* Ag = A + (long)(m0 + wave * 32 + (lane >> 2)) * K + (lane & 3) * 8;
  const u16* Bg = Bt + (long)(n0 + wave * 32 + (lane >> 2)) * K + (lane & 3) * 8;
  u16* Al = As + wave * 1024 + lane * 8;
  u16* Bl = Bs + wave * 1024 + lane * 8;
  for (int k0 = 0; k0 < K; k0 += 32) {
    __syncthreads();
    gld_lds16(Ag + k0, Al);
    gld_lds16(Ag + 16 * K + k0, Al + 512);
    gld_lds16(Bg + k0, Bl);
    gld_lds16(Bg + 16 * K + k0, Bl + 512);
    __syncthreads();
    bf16x8 af[4], bfr[4];
#pragma unroll
    for (int i = 0; i < 4; i++) {
      af[i] = *(const bf16x8*)(As + (wr + i * 16 + r) * 32 + q * 8);
      bfr[i] = *(const bf16x8*)(Bs + (wc + i * 16 + r) * 32 + q * 8);
    }
#pragma unroll
    for (int i = 0; i < 4; i++)
#pragma unroll
      for (int j = 0; j < 4; j++)
        acc[i][j] = __builtin_amdgcn_mfma_f32_16x16x32_bf16(af[i], bfr[j], acc[i][j], 0, 0, 0);
  }
#pragma unroll
  for (int i = 0; i < 4; i++) {
    int row = m0 + wr + i * 16 + q * 4;
#pragma unroll
    for (int j = 0; j < 4; j++) {
      int col = n0 + wc + j * 16 + r;
      float bv = bias ? bias[col] : 0.f;
#pragma unroll
      for (int rg = 0; rg < 4; rg++) {
        float vv = acc[i][j][rg] + bv;
        if (relu) vv = fmaxf(vv, 0.f);
        C[(long)(row + rg) * N + col] = f2b(vv);
      }
    }
  }
}

// ---------------- FUSED: x-GEMM + gc channel-mix (mini-MFMA) + res + BN (h in v-major) ----------
// grid: x = M-blocks (fast, streams A), y = 16 n-groups (slow, B L2-resident).
// K-loop identical to m97 (no in-loop extras). mini-A hg fragments read post-loop from global
// (L2-warm: this block just streamed those lines). xcs overlays As/Bs -> 33.3 KB LDS.
#define PAD 130
__global__ __launch_bounds__(256) void k_xgc(const u16* __restrict__ hg, const u16* __restrict__ bcat,
                                             u16* __restrict__ h,
                                             const u16* __restrict__ gcwB, const float* __restrict__ gcb,
                                             const float* __restrict__ bng, const float* __restrict__ bnb,
                                             int Lo, int d, int off, int layer) {
  __shared__ __align__(16) u16 smem[16640];  // loop: As[0,4096) Bs[4096,8192); post: xcs[0,16640)
  u16* As = smem;
  u16* Bs = smem + 4096;
  u16* xcs = smem;           // [n 0..127][m 0..127], PAD 130 (written after loop)
  int t = threadIdx.x, wave = t >> 6, lane = t & 63;
  int m0 = blockIdx.x * 128, g = blockIdx.y, n0 = g * 128;
  int wr = (wave >> 1) * 64, wc = (wave & 1) * 64;
  int q = lane >> 4, r = lane & 15;
  const int K = 1024;
  f32x4 acc[4][4] = {};
  const u16* Ag = hg + (long)(m0 + wave * 32 + (lane >> 2)) * K + (lane & 3) * 8;
  const u16* Bg = bcat + (long)(n0 + wave * 32 + (lane >> 2)) * K + (lane & 3) * 8;
  u16* Al = As + wave * 1024 + lane * 8;
  u16* Bl = Bs + wave * 1024 + lane * 8;
  for (int k0 = 0; k0 < K; k0 += 32) {
    __syncthreads();
    gld_lds16(Ag + k0, Al);
    gld_lds16(Ag + 16 * K + k0, Al + 512);
    gld_lds16(Bg + k0, Bl);
    gld_lds16(Bg + 16 * K + k0, Bl + 512);
    __syncthreads();
    bf16x8 af[4], bfr[4];
#pragma unroll
    for (int i = 0; i < 4; i++) {
      af[i] = *(const bf16x8*)(As + (wr + i * 16 + r) * 32 + q * 8);
      bfr[i] = *(const bf16x8*)(Bs + (wc + i * 16 + r) * 32 + q * 8);
    }
#pragma unroll
    for (int i = 0; i < 4; i++)
#pragma unroll
      for (int j = 0; j < 4; j++)
        acc[i][j] = __builtin_amdgcn_mfma_f32_16x16x32_bf16(af[i], bfr[j], acc[i][j], 0, 0, 0);
  }
  __syncthreads();  // all waves done with As/Bs before xcs overlay
  // mini-A hg fragments: direct global reads (issue early; latency overlaps xcs transpose below).
  // miniA[mt] lane(r,q)[j] = hgT[v = g*64 + mt*16 + r][c = q*8 + j], rows m0+wave*32+c.
  bf16x8 miniA[4];
  {
    const u16* hgA = hg + (long)(m0 + wave * 32 + q * 8) * K + g * 64;
#pragma unroll
    for (int mt = 0; mt < 4; mt++) {
      bf16x8 a;
#pragma unroll
      for (int j = 0; j < 8; j++)
        a[j] = (short)hgA[(long)j * K + mt * 16 + r];
      miniA[mt] = a;
    }
  }
  // acc -> xcs transposed: xcs[n_local][m_local]
#pragma unroll
  for (int i = 0; i < 4; i++) {
#pragma unroll
    for (int j = 0; j < 4; j++) {
      int row_m = wr + i * 16 + q * 4;
      int col_n = wc + j * 16 + r;
      ushort4 pk;
      pk.x = f2b(acc[i][j][0]); pk.y = f2b(acc[i][j][1]);
      pk.z = f2b(acc[i][j][2]); pk.w = f2b(acc[i][j][3]);
      *(ushort4*)(xcs + col_n * PAD + row_m) = pk;
    }
  }
  __syncthreads();
  // mini-GEMM per wave (= bl group): out[w 0..63][oc 0..31], K2=96 (hg from miniA, x1/x2 from xcs)
  int blg = blockIdx.x * 4 + wave;
  int b = blg / Lo, l = blg % Lo;
  bf16x8 bf2[2][3];
#pragma unroll
  for (int nt = 0; nt < 2; nt++)
#pragma unroll
    for (int ks = 0; ks < 3; ks++)
      bf2[nt][ks] = *(const bf16x8*)(gcwB + ((long)layer * 32 + nt * 16 + r) * 96 + ks * 32 + q * 8);
  f32x4 acc2[4][2] = {};
#pragma unroll
  for (int mt = 0; mt < 4; mt++) {
#pragma unroll
    for (int nt = 0; nt < 2; nt++)
      acc2[mt][nt] = __builtin_amdgcn_mfma_f32_16x16x32_bf16(miniA[mt], bf2[nt][0], acc2[mt][nt], 0, 0, 0);
#pragma unroll
    for (int ks = 1; ks < 3; ks++) {
      bf16x8 a2 = *(const bf16x8*)(xcs + ((ks - 1) * 64 + mt * 16 + r) * PAD + wave * 32 + q * 8);
#pragma unroll
      for (int nt = 0; nt < 2; nt++)
        acc2[mt][nt] = __builtin_amdgcn_mfma_f32_16x16x32_bf16(a2, bf2[nt][ks], acc2[mt][nt], 0, 0, 0);
    }
  }
  // epilogue: + gcb, residual, BN, in-place h write (v-major layout).
  const float rs = rsqrtf(1.f + 1e-5f);
  u16* hbase = h + ((long)(b * 13 + off + l + d) * 1024 + g * 64) * 32;
#pragma unroll
  for (int nt = 0; nt < 2; nt++) {
    int oc = nt * 16 + r;
    float gbv = gcb[layer * 32 + oc];
    float sc = bng[layer * 32 + oc] * rs;
    float bb = bnb[layer * 32 + oc];
#pragma unroll
    for (int mt = 0; mt < 4; mt++) {
#pragma unroll
      for (int rg = 0; rg < 4; rg++) {
        int w = mt * 16 + q * 4 + rg;
        u16* hp = hbase + (long)w * 32 + oc;
        float res = b2f(*hp);
        *hp = f2b((acc2[mt][nt][rg] + gbv + res) * sc + bb);
      }
    }
  }
}

// ---------------- final 12-wide conv, split-K x4 + LDS reduce: out fp32 ----------------
__global__ __launch_bounds__(256) void k_e3(const u16* __restrict__ e1, const float* __restrict__ w2,
                                            const float* __restrict__ b2, float* __restrict__ out, int b0) {
  __shared__ float red[256 * 13];
  int t = threadIdx.x;
  int r = t & 63, qq = t >> 6;
  long rowi = (long)blockIdx.x * 64 + r;
  const u16* rp = e1 + rowi * 512 + qq * 128;
  float acc[12];
#pragma unroll
  for (int o = 0; o < 12; o++) acc[o] = 0.f;
  for (int ec = 0; ec < 128; ec += 8) {
    bf16x8 raw = *(const bf16x8*)(rp + ec);
    float xv[8];
#pragma unroll
    for (int jj = 0; jj < 8; jj++) xv[jj] = b2f((u16)raw[jj]);
#pragma unroll
    for (int o = 0; o < 12; o++) {
      const float* w = w2 + o * 512 + qq * 128 + ec;
#pragma unroll
      for (int jj = 0; jj < 8; jj++) acc[o] += w[jj] * xv[jj];
    }
  }
#pragma unroll
  for (int o = 0; o < 12; o++) red[t * 13 + o] = acc[o];
  __syncthreads();
  if (t < 64) {
    long row = (long)blockIdx.x * 64 + t;
    int b = b0 + (int)(row >> 10), v = (int)(row & 1023);
#pragma unroll
    for (int o = 0; o < 12; o++) {
      float s = red[t * 13 + o] + red[(64 + t) * 13 + o] + red[(128 + t) * 13 + o] + red[(192 + t) * 13 + o];
      out[((long)b * 12 + o) * 1024 + v] = s + b2[o];
    }
  }
}

extern "C" void kernel_launch(void* const* d_in, const int* in_sizes, int n_in,
                              void* d_out, int out_size, void* d_ws, size_t ws_size,
                              hipStream_t stream) {
  const float* x = (const float*)d_in[0];
  const float* start_w = (const float*)d_in[1];
  const float* start_b = (const float*)d_in[2];
  const float* nv1 = (const float*)d_in[3];
  const float* nv2 = (const float*)d_in[4];
  const float* filter_w = (const float*)d_in[5];
  const float* filter_b = (const float*)d_in[6];
  const float* gate_w = (const float*)d_in[7];
  const float* gate_b = (const float*)d_in[8];
  const float* skip_w = (const float*)d_in[9];
  const float* skip_b = (const float*)d_in[10];
  const float* gc_w = (const float*)d_in[11];
  const float* gc_b = (const float*)d_in[12];
  const float* bn_g = (const float*)d_in[13];
  const float* bn_b = (const float*)d_in[14];
  const float* end1_w = (const float*)d_in[15];
  const float* end1_b = (const float*)d_in[16];
  const float* end2_w = (const float*)d_in[17];
  const float* end2_b = (const float*)d_in[18];
  float* out = (float*)d_out;

  char* ws = (char*)d_ws;
  // ---- fixed region ----
  u16* adp = (u16*)(ws + 0);                  //  2,097,152
  u16* bcat = (u16*)(ws + 2097152ull);        //  4,194,304 (reordered rows)
  u16* wcat = (u16*)(ws + 6291456ull);        //    131,072
  u16* e1bf = (u16*)(ws + 6422528ull);        //    262,144
  float* sbias = (float*)(ws + 6684672ull);   //      1,024
  u16* fwgB = (u16*)(ws + 6685696ull);        //     65,536
  u16* gcwB = (u16*)(ws + 6751232ull);        //     49,152
  const size_t o_dyn = 6800384ull;

  // ---- adaptive batch chunking: per-batch dyn = 2,162,688 B (h+hg+hlast) ----
  int BCH = 16;
  {
    const int cand[5] = {64, 48, 32, 24, 16};
    for (int ci = 0; ci < 5; ci++) {
      size_t need = o_dyn + (size_t)cand[ci] * 2162688ull;
      if (need <= ws_size) { BCH = cand[ci]; break; }
    }
  }
  u16* h = (u16*)(ws + o_dyn);                                 // BCH*851,968  (b,13,v,c)
  u16* hg = (u16*)(ws + o_dyn + (size_t)BCH * 851968ull);      // BCH*786,432  (b,l,c,v)
  u16* hlast = (u16*)(ws + o_dyn + (size_t)BCH * 1638400ull);  // BCH*524,288
  // pre-loop temps (in h region, dead before k_start):
  u16* adpT_p = (u16*)(ws + o_dyn);
  u16* adp2T_p = (u16*)(ws + o_dyn + 2097152ull);
  // end-phase aliases (h/hg dead then)
  u16* e1c = (u16*)(ws + o_dyn);
  u16* srelu = (u16*)(ws + o_dyn + (size_t)BCH * 1048576ull);

  static const int dilA[8] = {1, 2, 1, 2, 1, 2, 1, 2};
  static const int offA[8] = {0, 1, 3, 4, 6, 7, 9, 10};

  k_wprep<<<992, 256, 0, stream>>>(skip_w, skip_b, end1_w, filter_w, gate_w, gc_w,
                                   wcat, e1bf, sbias, fwgB, gcwB);
  k_adp<<<1024, 256, 0, stream>>>(nv1, nv2, adp);
  k_transpose<<<dim3(16, 16), 256, 0, stream>>>(adp, adpT_p);
  k_gemm<<<dim3(8, 8), 256, 0, stream>>>(adpT_p, adp, adp2T_p, 1024, 1024, 1024, nullptr, 0);
  k_pack<<<2048, 256, 0, stream>>>(adpT_p, adp2T_p, bcat);

  for (int b0 = 0; b0 < 64; b0 += BCH) {
    int bc = (64 - b0 < BCH) ? (64 - b0) : BCH;
    k_start<<<dim3(16, bc), 256, 0, stream>>>(x, start_w, start_b, h, b0);
    for (int i = 0; i < 8; i++) {
      int d = dilA[i], off = offA[i], Lo = 13 - off - d;
      k_gate<<<dim3(4, Lo, bc), 256, 0, stream>>>(h, hg, hlast, fwgB, filter_b, gate_b,
                                                  Lo, d, off, i, (i < 7) ? 1 : 0);
      if (i < 7) {
        k_xgc<<<dim3(bc * Lo / 4, 16), 256, 0, stream>>>(hg, bcat, h, gcwB, gc_b,
                                                         bn_g, bn_b, Lo, d, off, i);
      }
    }
    int Mc = bc * 1024;
    k_gemm<<<dim3(2, Mc / 128), 256, 0, stream>>>(hlast, wcat, srelu, Mc, 256, 256, sbias, 1);
    k_gemm<<<dim3(4, Mc / 128), 256, 0, stream>>>(srelu, e1bf, e1c, Mc, 512, 256, end1_b, 1);
    k_e3<<<bc * 16, 256, 0, stream>>>(e1c, end2_w, end2_b, out, b0);
  }
  (void)in_sizes; (void)n_in; (void)out_size;
}

// Round 13
// 1099.590 us; speedup vs baseline: 1.1612x; 1.0479x over previous
//
#include <hip/hip_runtime.h>

typedef unsigned short u16;
typedef unsigned int u32;
typedef __attribute__((ext_vector_type(8))) short bf16x8;
typedef __attribute__((ext_vector_type(4))) float f32x4;

__device__ __forceinline__ float b2f(u16 u) { return __uint_as_float(((u32)u) << 16); }
__device__ __forceinline__ u16 f2b(float f) {
  u32 u = __float_as_uint(f);
  return (u16)((u + 0x7FFFu + ((u >> 16) & 1u)) >> 16);
}

__device__ __forceinline__ void gld_lds16(const void* g, void* l) {
  __builtin_amdgcn_global_load_lds((const __attribute__((address_space(1))) u32*)g,
                                   (__attribute__((address_space(3))) u32*)l, 16, 0, 0);
}

// ---------------- adp = softmax(relu(nv1@nv2), axis=1), bf16, row-major (v,w) ----------------
__global__ __launch_bounds__(256) void k_adp(const float* __restrict__ nv1,
                                             const float* __restrict__ nv2,
                                             u16* __restrict__ adp) {
  int v = blockIdx.x, t = threadIdx.x;
  __shared__ float red[8];
  const float* nrow = nv1 + v * 10;
  float z[4];
#pragma unroll
  for (int j = 0; j < 4; j++) {
    int w = t + j * 256;
    float s = 0.f;
#pragma unroll
    for (int a = 0; a < 10; a++) s += nrow[a] * nv2[a * 1024 + w];
    z[j] = fmaxf(s, 0.f);
  }
  float m = fmaxf(fmaxf(z[0], z[1]), fmaxf(z[2], z[3]));
  for (int off = 32; off; off >>= 1) m = fmaxf(m, __shfl_down(m, off));
  if ((t & 63) == 0) red[t >> 6] = m;
  __syncthreads();
  m = fmaxf(fmaxf(red[0], red[1]), fmaxf(red[2], red[3]));
  float e[4], s = 0.f;
#pragma unroll
  for (int j = 0; j < 4; j++) { e[j] = __expf(z[j] - m); s += e[j]; }
  for (int off = 32; off; off >>= 1) s += __shfl_down(s, off);
  if ((t & 63) == 0) red[4 + (t >> 6)] = s;
  __syncthreads();
  s = red[4] + red[5] + red[6] + red[7];
  float inv = 1.0f / s;
#pragma unroll
  for (int j = 0; j < 4; j++) adp[(long)v * 1024 + t + j * 256] = f2b(e[j] * inv);
}

// ---------------- transpose 1024x1024 bf16 ----------------
__global__ __launch_bounds__(256) void k_transpose(const u16* __restrict__ in, u16* __restrict__ out) {
  __shared__ u16 tile[64 * 65];
  int w0 = blockIdx.x * 64, v0 = blockIdx.y * 64, t = threadIdx.x;
  int c = t & 63, r4 = t >> 6;
  for (int rr = r4; rr < 64; rr += 4) tile[rr * 65 + c] = in[(long)(v0 + rr) * 1024 + w0 + c];
  __syncthreads();
  for (int rr = r4; rr < 64; rr += 4) out[(long)(w0 + rr) * 1024 + v0 + c] = tile[c * 65 + rr];
}

// ---------------- pack bcat rows: n = (v>>6)*128 + src*64 + (v&63) ----------------
__global__ __launch_bounds__(256) void k_pack(const u16* __restrict__ adpT, const u16* __restrict__ adp2T,
                                              u16* __restrict__ bcat) {
  int n = blockIdx.x;
  int g = n >> 7, rem = n & 127, src = rem >> 6, v = g * 64 + (rem & 63);
  const u16* s = (src ? adp2T : adpT) + (long)v * 1024;
  u16* d = bcat + (long)n * 1024;
  ((ushort4*)d)[threadIdx.x] = ((const ushort4*)s)[threadIdx.x];
}

// ---------------- weight repacks + summed skip bias ----------------
// fwgB[layer][n 0..63][k 0..63] bf16: n<32 -> filter oc, n>=32 -> gate oc; k = tap*32 + ci.
__global__ __launch_bounds__(256) void k_wprep(const float* __restrict__ skw, const float* __restrict__ skb,
                                               const float* __restrict__ e1w,
                                               const float* __restrict__ fw, const float* __restrict__ gw,
                                               const float* __restrict__ gcw,
                                               u16* __restrict__ wcat, u16* __restrict__ e1bf,
                                               float* __restrict__ sbias,
                                               u16* __restrict__ fwgB, u16* __restrict__ gcwB) {
  int idx = blockIdx.x * 256 + threadIdx.x;
  if (idx < 65536) {
    int cp = idx >> 8, k = idx & 255, i = k >> 5, c = k & 31;
    wcat[idx] = f2b(skw[(i * 256 + cp) * 32 + c]);
  } else if (idx < 196608) {
    int j = idx - 65536;
    e1bf[j] = f2b(e1w[j]);
  } else if (idx < 229376) {
    int j = idx - 196608;
    int layer = j >> 12, rem = j & 4095, n = rem >> 6, k = rem & 63;
    int tap = k >> 5, ci = k & 31, oc = n & 31;
    const float* src = (n < 32) ? fw : gw;
    fwgB[j] = f2b(src[((layer * 32 + oc) * 32 + ci) * 2 + tap]);
  } else if (idx < 253952) {
    int j = idx - 229376;  // native-order bf16 copy of gc_w
    gcwB[j] = f2b(gcw[j]);
  }
  if (idx < 256) {
    float s = 0.f;
    for (int i = 0; i < 8; i++) s += skb[i * 256 + idx];
    sbias[idx] = s;
  }
}

// ---------------- start conv: h[b][slot][v][c] bf16 — full-line (64B) writes per thread --------
__global__ __launch_bounds__(256) void k_start(const float* __restrict__ x, const float* __restrict__ sw,
                                               const float* __restrict__ sb, u16* __restrict__ h, int b0) {
  int bl = blockIdx.y, bg = b0 + bl, v0 = blockIdx.x * 64, t = threadIdx.x;
  __shared__ float xs[2 * 832];  // [i][vl*13+l]
  for (int idx = t; idx < 2 * 832; idx += 256) {
    int i = idx / 832, rem = idx % 832;
    xs[idx] = x[((long)(bg * 2 + i) * 1024 + v0) * 13 + rem];
  }
  __syncthreads();
  for (int p = t; p < 832; p += 256) {
    int l = p % 13, vl = p / 13;
    float x0 = xs[vl * 13 + l];
    float x1 = xs[832 + vl * 13 + l];
    u16* dst = h + ((long)(bl * 13 + l) * 1024 + v0 + vl) * 32;
#pragma unroll
    for (int cq = 0; cq < 4; cq++) {
      bf16x8 pk;
#pragma unroll
      for (int j = 0; j < 8; j++) {
        int c = cq * 8 + j;
        pk[j] = (short)f2b(sw[c * 2 + 0] * x0 + sw[c * 2 + 1] * x1 + sb[c]);
      }
      *(bf16x8*)(dst + cq * 8) = pk;
    }
  }
}

// ---------------- gated dilated conv via MFMA: M=v, N=64 (f|g), K=64 (2 taps x 32 ci) ----------
__global__ __launch_bounds__(256, 2) void k_gate(const u16* __restrict__ h, u16* __restrict__ hg,
                                                 u16* __restrict__ hlast,
                                                 const u16* __restrict__ fwgB,
                                                 const float* __restrict__ fb, const float* __restrict__ gb,
                                                 int Lo, int d, int off, int layer, int writehg) {
  int t = threadIdx.x, wave = t >> 6, lane = t & 63;
  int q = lane >> 4, r = lane & 15;
  int b = blockIdx.z, l = blockIdx.y;
  int vbase = blockIdx.x * 256 + wave * 64;
  f32x4 acc[4][4] = {};
  const u16* wb = fwgB + layer * 4096;
#pragma unroll
  for (int ks = 0; ks < 2; ks++) {
    const u16* hrow = h + ((long)(b * 13 + off + l + ks * d) * 1024) * 32;
    bf16x8 af[4], bf[4];
#pragma unroll
    for (int mt = 0; mt < 4; mt++)
      af[mt] = *(const bf16x8*)(hrow + (long)(vbase + mt * 16 + r) * 32 + q * 8);
#pragma unroll
    for (int nt = 0; nt < 4; nt++)
      bf[nt] = *(const bf16x8*)(wb + (nt * 16 + r) * 64 + ks * 32 + q * 8);
#pragma unroll
    for (int mt = 0; mt < 4; mt++)
#pragma unroll
      for (int nt = 0; nt < 4; nt++)
        acc[mt][nt] = __builtin_amdgcn_mfma_f32_16x16x32_bf16(af[mt], bf[nt], acc[mt][nt], 0, 0, 0);
  }
  int last = (l == Lo - 1);
#pragma unroll
  for (int nt = 0; nt < 2; nt++) {
    int oc = nt * 16 + r;
    float fbv = fb[layer * 32 + oc], gbv = gb[layer * 32 + oc];
#pragma unroll
    for (int mt = 0; mt < 4; mt++) {
      u16 vv[4];
#pragma unroll
      for (int rg = 0; rg < 4; rg++) {
        float f = acc[mt][nt][rg] + fbv;
        float g = acc[mt][nt + 2][rg] + gbv;
        float ft = 2.f * __builtin_amdgcn_rcpf(1.f + __expf(-2.f * f)) - 1.f;
        float sg = __builtin_amdgcn_rcpf(1.f + __expf(-g));
        vv[rg] = f2b(ft * sg);
      }
      int v0 = vbase + mt * 16 + q * 4;
      if (writehg) {
        ushort4 pk; pk.x = vv[0]; pk.y = vv[1]; pk.z = vv[2]; pk.w = vv[3];
        *(ushort4*)(hg + ((long)(b * Lo + l) * 32 + oc) * 1024 + v0) = pk;
      }
      if (last) {
#pragma unroll
        for (int rg = 0; rg < 4; rg++)
          hlast[((long)(b * 1024 + v0 + rg)) * 256 + layer * 32 + oc] = vv[rg];
      }
    }
  }
}

// ---------------- generic GEMM (m97 structure), used for adp2 + end-head ----------------
__global__ __launch_bounds__(256) void k_gemm(const u16* __restrict__ A, const u16* __restrict__ Bt,
                                              u16* __restrict__ C, int M, int N, int K,
                                              const float* __restrict__ bias, int relu) {
  __shared__ __align__(16) u16 As[128 * 32];
  __shared__ __align__(16) u16 Bs[128 * 32];
  int t = threadIdx.x, wave = t >> 6, lane = t & 63;
  int m0 = blockIdx.y * 128, n0 = blockIdx.x * 128;
  int wr = (wave >> 1) * 64, wc = (wave & 1) * 64;
  int q = lane >> 4, r = lane & 15;
  f32x4 acc[4][4] = {};
  const u16* Ag = A + (long)(m0 + wave * 32 + (lane >> 2)) * K + (lane & 3) * 8;
  const u16* Bg = Bt + (long)(n0 + wave * 32 + (lane >> 2)) * K + (lane & 3) * 8;
  u16* Al = As + wave * 1024 + lane * 8;
  u16* Bl = Bs + wave * 1024 + lane * 8;
  for (int k0 = 0; k0 < K; k0 += 32) {
    __syncthreads();
    gld_lds16(Ag + k0, Al);
    gld_lds16(Ag + 16 * K + k0, Al + 512);
    gld_lds16(Bg + k0, Bl);
    gld_lds16(Bg + 16 * K + k0, Bl + 512);
    __syncthreads();
    bf16x8 af[4], bfr[4];
#pragma unroll
    for (int i = 0; i < 4; i++) {
      af[i] = *(const bf16x8*)(As + (wr + i * 16 + r) * 32 + q * 8);
      bfr[i] = *(const bf16x8*)(Bs + (wc + i * 16 + r) * 32 + q * 8);
    }
#pragma unroll
    for (int i = 0; i < 4; i++)
#pragma unroll
      for (int j = 0; j < 4; j++)
        acc[i][j] = __builtin_amdgcn_mfma_f32_16x16x32_bf16(af[i], bfr[j], acc[i][j], 0, 0, 0);
  }
#pragma unroll
  for (int i = 0; i < 4; i++) {
    int row = m0 + wr + i * 16 + q * 4;
#pragma unroll
    for (int j = 0; j < 4; j++) {
      int col = n0 + wc + j * 16 + r;
      float bv = bias ? bias[col] : 0.f;
#pragma unroll
      for (int rg = 0; rg < 4; rg++) {
        float vv = acc[i][j][rg] + bv;
        if (relu) vv = fmaxf(vv, 0.f);
        C[(long)(row + rg) * N + col] = f2b(vv);
      }
    }
  }
}

// ---------------- FUSED: x-GEMM + gc channel-mix (mini-MFMA) + res + BN (h in v-major) ----------
// grid: x = M-blocks (fast, streams A), y = 16 n-groups (slow, B L2-resident).
// Post-loop LDS time-multiplexed: phase A hgT[0,8320) (coalesced global stage -> miniA regs),
// phase B xcs[0,16640). Peak LDS 33.3 KB. K-loop byte-identical to m97.
#define PAD 130
__global__ __launch_bounds__(256) void k_xgc(const u16* __restrict__ hg, const u16* __restrict__ bcat,
                                             u16* __restrict__ h,
                                             const u16* __restrict__ gcwB, const float* __restrict__ gcb,
                                             const float* __restrict__ bng, const float* __restrict__ bnb,
                                             int Lo, int d, int off, int layer) {
  __shared__ __align__(16) u16 smem[16640];  // loop: As[0,4096) Bs[4096,8192); A: hgT[0,8320); B: xcs[0,16640)
  u16* As = smem;
  u16* Bs = smem + 4096;
  u16* hgT = smem;           // [v 0..63][m 0..127], PAD 130 (phase A)
  u16* xcs = smem;           // [n 0..127][m 0..127], PAD 130 (phase B)
  int t = threadIdx.x, wave = t >> 6, lane = t & 63;
  int m0 = blockIdx.x * 128, g = blockIdx.y, n0 = g * 128;
  int wr = (wave >> 1) * 64, wc = (wave & 1) * 64;
  int q = lane >> 4, r = lane & 15;
  const int K = 1024;
  f32x4 acc[4][4] = {};
  const u16* Ag = hg + (long)(m0 + wave * 32 + (lane >> 2)) * K + (lane & 3) * 8;
  const u16* Bg = bcat + (long)(n0 + wave * 32 + (lane >> 2)) * K + (lane & 3) * 8;
  u16* Al = As + wave * 1024 + lane * 8;
  u16* Bl = Bs + wave * 1024 + lane * 8;
  for (int k0 = 0; k0 < K; k0 += 32) {
    __syncthreads();
    gld_lds16(Ag + k0, Al);
    gld_lds16(Ag + 16 * K + k0, Al + 512);
    gld_lds16(Bg + k0, Bl);
    gld_lds16(Bg + 16 * K + k0, Bl + 512);
    __syncthreads();
    bf16x8 af[4], bfr[4];
#pragma unroll
    for (int i = 0; i < 4; i++) {
      af[i] = *(const bf16x8*)(As + (wr + i * 16 + r) * 32 + q * 8);
      bfr[i] = *(const bf16x8*)(Bs + (wc + i * 16 + r) * 32 + q * 8);
    }
#pragma unroll
    for (int i = 0; i < 4; i++)
#pragma unroll
      for (int j = 0; j < 4; j++)
        acc[i][j] = __builtin_amdgcn_mfma_f32_16x16x32_bf16(af[i], bfr[j], acc[i][j], 0, 0, 0);
  }
  __syncthreads();  // As/Bs dead
  // phase A: stage hg tile transposed into hgT (coalesced global read, r10 pattern)
  {
    int row = t >> 1, half = t & 1;
    const u16* src = hg + (long)(m0 + row) * K + g * 64 + half * 32;
#pragma unroll
    for (int e = 0; e < 4; e++) {
      bf16x8 v8 = *(const bf16x8*)(src + e * 8);
#pragma unroll
      for (int jj = 0; jj < 8; jj++)
        hgT[(half * 32 + e * 8 + jj) * PAD + row] = (u16)v8[jj];
    }
  }
  __syncthreads();
  // miniA fragments -> registers (b128-style LDS reads, r10 pattern)
  bf16x8 miniA[4];
#pragma unroll
  for (int mt = 0; mt < 4; mt++)
    miniA[mt] = *(const bf16x8*)(hgT + (mt * 16 + r) * PAD + wave * 32 + q * 8);
  __syncthreads();  // hgT dead
  // phase B: acc -> xcs transposed: xcs[n_local][m_local]
#pragma unroll
  for (int i = 0; i < 4; i++) {
#pragma unroll
    for (int j = 0; j < 4; j++) {
      int row_m = wr + i * 16 + q * 4;
      int col_n = wc + j * 16 + r;
      ushort4 pk;
      pk.x = f2b(acc[i][j][0]); pk.y = f2b(acc[i][j][1]);
      pk.z = f2b(acc[i][j][2]); pk.w = f2b(acc[i][j][3]);
      *(ushort4*)(xcs + col_n * PAD + row_m) = pk;
    }
  }
  __syncthreads();
  // mini-GEMM per wave (= bl group): out[w 0..63][oc 0..31], K2=96 (hg from miniA, x1/x2 from xcs)
  int blg = blockIdx.x * 4 + wave;
  int b = blg / Lo, l = blg % Lo;
  bf16x8 bf2[2][3];
#pragma unroll
  for (int nt = 0; nt < 2; nt++)
#pragma unroll
    for (int ks = 0; ks < 3; ks++)
      bf2[nt][ks] = *(const bf16x8*)(gcwB + ((long)layer * 32 + nt * 16 + r) * 96 + ks * 32 + q * 8);
  f32x4 acc2[4][2] = {};
#pragma unroll
  for (int mt = 0; mt < 4; mt++) {
#pragma unroll
    for (int nt = 0; nt < 2; nt++)
      acc2[mt][nt] = __builtin_amdgcn_mfma_f32_16x16x32_bf16(miniA[mt], bf2[nt][0], acc2[mt][nt], 0, 0, 0);
#pragma unroll
    for (int ks = 1; ks < 3; ks++) {
      bf16x8 a2 = *(const bf16x8*)(xcs + ((ks - 1) * 64 + mt * 16 + r) * PAD + wave * 32 + q * 8);
#pragma unroll
      for (int nt = 0; nt < 2; nt++)
        acc2[mt][nt] = __builtin_amdgcn_mfma_f32_16x16x32_bf16(a2, bf2[nt][ks], acc2[mt][nt], 0, 0, 0);
    }
  }
  // epilogue: + gcb, residual, BN, in-place h write (v-major layout).
  const float rs = rsqrtf(1.f + 1e-5f);
  u16* hbase = h + ((long)(b * 13 + off + l + d) * 1024 + g * 64) * 32;
#pragma unroll
  for (int nt = 0; nt < 2; nt++) {
    int oc = nt * 16 + r;
    float gbv = gcb[layer * 32 + oc];
    float sc = bng[layer * 32 + oc] * rs;
    float bb = bnb[layer * 32 + oc];
#pragma unroll
    for (int mt = 0; mt < 4; mt++) {
#pragma unroll
      for (int rg = 0; rg < 4; rg++) {
        int w = mt * 16 + q * 4 + rg;
        u16* hp = hbase + (long)w * 32 + oc;
        float res = b2f(*hp);
        *hp = f2b((acc2[mt][nt][rg] + gbv + res) * sc + bb);
      }
    }
  }
}

// ---------------- final 12-wide conv, split-K x4 + LDS reduce: out fp32 ----------------
__global__ __launch_bounds__(256) void k_e3(const u16* __restrict__ e1, const float* __restrict__ w2,
                                            const float* __restrict__ b2, float* __restrict__ out, int b0) {
  __shared__ float red[256 * 13];
  int t = threadIdx.x;
  int r = t & 63, qq = t >> 6;
  long rowi = (long)blockIdx.x * 64 + r;
  const u16* rp = e1 + rowi * 512 + qq * 128;
  float acc[12];
#pragma unroll
  for (int o = 0; o < 12; o++) acc[o] = 0.f;
  for (int ec = 0; ec < 128; ec += 8) {
    bf16x8 raw = *(const bf16x8*)(rp + ec);
    float xv[8];
#pragma unroll
    for (int jj = 0; jj < 8; jj++) xv[jj] = b2f((u16)raw[jj]);
#pragma unroll
    for (int o = 0; o < 12; o++) {
      const float* w = w2 + o * 512 + qq * 128 + ec;
#pragma unroll
      for (int jj = 0; jj < 8; jj++) acc[o] += w[jj] * xv[jj];
    }
  }
#pragma unroll
  for (int o = 0; o < 12; o++) red[t * 13 + o] = acc[o];
  __syncthreads();
  if (t < 64) {
    long row = (long)blockIdx.x * 64 + t;
    int b = b0 + (int)(row >> 10), v = (int)(row & 1023);
#pragma unroll
    for (int o = 0; o < 12; o++) {
      float s = red[t * 13 + o] + red[(64 + t) * 13 + o] + red[(128 + t) * 13 + o] + red[(192 + t) * 13 + o];
      out[((long)b * 12 + o) * 1024 + v] = s + b2[o];
    }
  }
}

extern "C" void kernel_launch(void* const* d_in, const int* in_sizes, int n_in,
                              void* d_out, int out_size, void* d_ws, size_t ws_size,
                              hipStream_t stream) {
  const float* x = (const float*)d_in[0];
  const float* start_w = (const float*)d_in[1];
  const float* start_b = (const float*)d_in[2];
  const float* nv1 = (const float*)d_in[3];
  const float* nv2 = (const float*)d_in[4];
  const float* filter_w = (const float*)d_in[5];
  const float* filter_b = (const float*)d_in[6];
  const float* gate_w = (const float*)d_in[7];
  const float* gate_b = (const float*)d_in[8];
  const float* skip_w = (const float*)d_in[9];
  const float* skip_b = (const float*)d_in[10];
  const float* gc_w = (const float*)d_in[11];
  const float* gc_b = (const float*)d_in[12];
  const float* bn_g = (const float*)d_in[13];
  const float* bn_b = (const float*)d_in[14];
  const float* end1_w = (const float*)d_in[15];
  const float* end1_b = (const float*)d_in[16];
  const float* end2_w = (const float*)d_in[17];
  const float* end2_b = (const float*)d_in[18];
  float* out = (float*)d_out;

  char* ws = (char*)d_ws;
  // ---- fixed region ----
  u16* adp = (u16*)(ws + 0);                  //  2,097,152
  u16* bcat = (u16*)(ws + 2097152ull);        //  4,194,304 (reordered rows)
  u16* wcat = (u16*)(ws + 6291456ull);        //    131,072
  u16* e1bf = (u16*)(ws + 6422528ull);        //    262,144
  float* sbias = (float*)(ws + 6684672ull);   //      1,024
  u16* fwgB = (u16*)(ws + 6685696ull);        //     65,536
  u16* gcwB = (u16*)(ws + 6751232ull);        //     49,152
  const size_t o_dyn = 6800384ull;

  // ---- adaptive batch chunking: per-batch dyn = 2,162,688 B (h+hg+hlast) ----
  int BCH = 16;
  {
    const int cand[5] = {64, 48, 32, 24, 16};
    for (int ci = 0; ci < 5; ci++) {
      size_t need = o_dyn + (size_t)cand[ci] * 2162688ull;
      if (need <= ws_size) { BCH = cand[ci]; break; }
    }
  }
  u16* h = (u16*)(ws + o_dyn);                                 // BCH*851,968  (b,13,v,c)
  u16* hg = (u16*)(ws + o_dyn + (size_t)BCH * 851968ull);      // BCH*786,432  (b,l,c,v)
  u16* hlast = (u16*)(ws + o_dyn + (size_t)BCH * 1638400ull);  // BCH*524,288
  // pre-loop temps (in h region, dead before k_start):
  u16* adpT_p = (u16*)(ws + o_dyn);
  u16* adp2T_p = (u16*)(ws + o_dyn + 2097152ull);
  // end-phase aliases (h/hg dead then)
  u16* e1c = (u16*)(ws + o_dyn);
  u16* srelu = (u16*)(ws + o_dyn + (size_t)BCH * 1048576ull);

  static const int dilA[8] = {1, 2, 1, 2, 1, 2, 1, 2};
  static const int offA[8] = {0, 1, 3, 4, 6, 7, 9, 10};

  k_wprep<<<992, 256, 0, stream>>>(skip_w, skip_b, end1_w, filter_w, gate_w, gc_w,
                                   wcat, e1bf, sbias, fwgB, gcwB);
  k_adp<<<1024, 256, 0, stream>>>(nv1, nv2, adp);
  k_transpose<<<dim3(16, 16), 256, 0, stream>>>(adp, adpT_p);
  k_gemm<<<dim3(8, 8), 256, 0, stream>>>(adpT_p, adp, adp2T_p, 1024, 1024, 1024, nullptr, 0);
  k_pack<<<2048, 256, 0, stream>>>(adpT_p, adp2T_p, bcat);

  for (int b0 = 0; b0 < 64; b0 += BCH) {
    int bc = (64 - b0 < BCH) ? (64 - b0) : BCH;
    k_start<<<dim3(16, bc), 256, 0, stream>>>(x, start_w, start_b, h, b0);
    for (int i = 0; i < 8; i++) {
      int d = dilA[i], off = offA[i], Lo = 13 - off - d;
      k_gate<<<dim3(4, Lo, bc), 256, 0, stream>>>(h, hg, hlast, fwgB, filter_b, gate_b,
                                                  Lo, d, off, i, (i < 7) ? 1 : 0);
      if (i < 7) {
        k_xgc<<<dim3(bc * Lo / 4, 16), 256, 0, stream>>>(hg, bcat, h, gcwB, gc_b,
                                                         bn_g, bn_b, Lo, d, off, i);
      }
    }
    int Mc = bc * 1024;
    k_gemm<<<dim3(2, Mc / 128), 256, 0, stream>>>(hlast, wcat, srelu, Mc, 256, 256, sbias, 1);
    k_gemm<<<dim3(4, Mc / 128), 256, 0, stream>>>(srelu, e1bf, e1c, Mc, 512, 256, end1_b, 1);
    k_e3<<<bc * 16, 256, 0, stream>>>(e1c, end2_w, end2_b, out, b0);
  }
  (void)in_sizes; (void)n_in; (void)out_size;
}

// Round 14
// 1098.948 us; speedup vs baseline: 1.1618x; 1.0006x over previous
//
#include <hip/hip_runtime.h>

typedef unsigned short u16;
typedef unsigned int u32;
typedef __attribute__((ext_vector_type(8))) short bf16x8;
typedef __attribute__((ext_vector_type(4))) float f32x4;

__device__ __forceinline__ float b2f(u16 u) { return __uint_as_float(((u32)u) << 16); }
__device__ __forceinline__ u16 f2b(float f) {
  u32 u = __float_as_uint(f);
  return (u16)((u + 0x7FFFu + ((u >> 16) & 1u)) >> 16);
}

__device__ __forceinline__ void gld_lds16(const void* g, void* l) {
  __builtin_amdgcn_global_load_lds((const __attribute__((address_space(1))) u32*)g,
                                   (__attribute__((address_space(3))) u32*)l, 16, 0, 0);
}

// ---------------- adp = softmax(relu(nv1@nv2), axis=1), bf16, row-major (v,w) ----------------
__global__ __launch_bounds__(256) void k_adp(const float* __restrict__ nv1,
                                             const float* __restrict__ nv2,
                                             u16* __restrict__ adp) {
  int v = blockIdx.x, t = threadIdx.x;
  __shared__ float red[8];
  const float* nrow = nv1 + v * 10;
  float z[4];
#pragma unroll
  for (int j = 0; j < 4; j++) {
    int w = t + j * 256;
    float s = 0.f;
#pragma unroll
    for (int a = 0; a < 10; a++) s += nrow[a] * nv2[a * 1024 + w];
    z[j] = fmaxf(s, 0.f);
  }
  float m = fmaxf(fmaxf(z[0], z[1]), fmaxf(z[2], z[3]));
  for (int off = 32; off; off >>= 1) m = fmaxf(m, __shfl_down(m, off));
  if ((t & 63) == 0) red[t >> 6] = m;
  __syncthreads();
  m = fmaxf(fmaxf(red[0], red[1]), fmaxf(red[2], red[3]));
  float e[4], s = 0.f;
#pragma unroll
  for (int j = 0; j < 4; j++) { e[j] = __expf(z[j] - m); s += e[j]; }
  for (int off = 32; off; off >>= 1) s += __shfl_down(s, off);
  if ((t & 63) == 0) red[4 + (t >> 6)] = s;
  __syncthreads();
  s = red[4] + red[5] + red[6] + red[7];
  float inv = 1.0f / s;
#pragma unroll
  for (int j = 0; j < 4; j++) adp[(long)v * 1024 + t + j * 256] = f2b(e[j] * inv);
}

// ---------------- transpose 1024x1024 bf16 ----------------
__global__ __launch_bounds__(256) void k_transpose(const u16* __restrict__ in, u16* __restrict__ out) {
  __shared__ u16 tile[64 * 65];
  int w0 = blockIdx.x * 64, v0 = blockIdx.y * 64, t = threadIdx.x;
  int c = t & 63, r4 = t >> 6;
  for (int rr = r4; rr < 64; rr += 4) tile[rr * 65 + c] = in[(long)(v0 + rr) * 1024 + w0 + c];
  __syncthreads();
  for (int rr = r4; rr < 64; rr += 4) out[(long)(w0 + rr) * 1024 + v0 + c] = tile[c * 65 + rr];
}

// ---------------- pack bcat rows: n = (v>>6)*128 + src*64 + (v&63) ----------------
__global__ __launch_bounds__(256) void k_pack(const u16* __restrict__ adpT, const u16* __restrict__ adp2T,
                                              u16* __restrict__ bcat) {
  int n = blockIdx.x;
  int g = n >> 7, rem = n & 127, src = rem >> 6, v = g * 64 + (rem & 63);
  const u16* s = (src ? adp2T : adpT) + (long)v * 1024;
  u16* d = bcat + (long)n * 1024;
  ((ushort4*)d)[threadIdx.x] = ((const ushort4*)s)[threadIdx.x];
}

// ---------------- weight repacks + summed skip bias ----------------
// fwgB[layer][n 0..63][k 0..63] bf16: n<32 -> filter oc, n>=32 -> gate oc; k = tap*32 + ci.
__global__ __launch_bounds__(256) void k_wprep(const float* __restrict__ skw, const float* __restrict__ skb,
                                               const float* __restrict__ e1w,
                                               const float* __restrict__ fw, const float* __restrict__ gw,
                                               const float* __restrict__ gcw,
                                               u16* __restrict__ wcat, u16* __restrict__ e1bf,
                                               float* __restrict__ sbias,
                                               u16* __restrict__ fwgB, u16* __restrict__ gcwB) {
  int idx = blockIdx.x * 256 + threadIdx.x;
  if (idx < 65536) {
    int cp = idx >> 8, k = idx & 255, i = k >> 5, c = k & 31;
    wcat[idx] = f2b(skw[(i * 256 + cp) * 32 + c]);
  } else if (idx < 196608) {
    int j = idx - 65536;
    e1bf[j] = f2b(e1w[j]);
  } else if (idx < 229376) {
    int j = idx - 196608;
    int layer = j >> 12, rem = j & 4095, n = rem >> 6, k = rem & 63;
    int tap = k >> 5, ci = k & 31, oc = n & 31;
    const float* src = (n < 32) ? fw : gw;
    fwgB[j] = f2b(src[((layer * 32 + oc) * 32 + ci) * 2 + tap]);
  } else if (idx < 253952) {
    int j = idx - 229376;  // native-order bf16 copy of gc_w
    gcwB[j] = f2b(gcw[j]);
  }
  if (idx < 256) {
    float s = 0.f;
    for (int i = 0; i < 8; i++) s += skb[i * 256 + idx];
    sbias[idx] = s;
  }
}

// ---------------- start conv: h[b][slot][v][c] bf16 — full-line (64B) writes per thread --------
__global__ __launch_bounds__(256) void k_start(const float* __restrict__ x, const float* __restrict__ sw,
                                               const float* __restrict__ sb, u16* __restrict__ h, int b0) {
  int bl = blockIdx.y, bg = b0 + bl, v0 = blockIdx.x * 64, t = threadIdx.x;
  __shared__ float xs[2 * 832];  // [i][vl*13+l]
  for (int idx = t; idx < 2 * 832; idx += 256) {
    int i = idx / 832, rem = idx % 832;
    xs[idx] = x[((long)(bg * 2 + i) * 1024 + v0) * 13 + rem];
  }
  __syncthreads();
  for (int p = t; p < 832; p += 256) {
    int l = p % 13, vl = p / 13;
    float x0 = xs[vl * 13 + l];
    float x1 = xs[832 + vl * 13 + l];
    u16* dst = h + ((long)(bl * 13 + l) * 1024 + v0 + vl) * 32;
#pragma unroll
    for (int cq = 0; cq < 4; cq++) {
      bf16x8 pk;
#pragma unroll
      for (int j = 0; j < 8; j++) {
        int c = cq * 8 + j;
        pk[j] = (short)f2b(sw[c * 2 + 0] * x0 + sw[c * 2 + 1] * x1 + sb[c]);
      }
      *(bf16x8*)(dst + cq * 8) = pk;
    }
  }
}

// ---------------- gated dilated conv via MFMA: M=v, N=64 (f|g), K=64 (2 taps x 32 ci) ----------
__global__ __launch_bounds__(256, 2) void k_gate(const u16* __restrict__ h, u16* __restrict__ hg,
                                                 u16* __restrict__ hlast,
                                                 const u16* __restrict__ fwgB,
                                                 const float* __restrict__ fb, const float* __restrict__ gb,
                                                 int Lo, int d, int off, int layer, int writehg) {
  int t = threadIdx.x, wave = t >> 6, lane = t & 63;
  int q = lane >> 4, r = lane & 15;
  int b = blockIdx.z, l = blockIdx.y;
  int vbase = blockIdx.x * 256 + wave * 64;
  f32x4 acc[4][4] = {};
  const u16* wb = fwgB + layer * 4096;
#pragma unroll
  for (int ks = 0; ks < 2; ks++) {
    const u16* hrow = h + ((long)(b * 13 + off + l + ks * d) * 1024) * 32;
    bf16x8 af[4], bf[4];
#pragma unroll
    for (int mt = 0; mt < 4; mt++)
      af[mt] = *(const bf16x8*)(hrow + (long)(vbase + mt * 16 + r) * 32 + q * 8);
#pragma unroll
    for (int nt = 0; nt < 4; nt++)
      bf[nt] = *(const bf16x8*)(wb + (nt * 16 + r) * 64 + ks * 32 + q * 8);
#pragma unroll
    for (int mt = 0; mt < 4; mt++)
#pragma unroll
      for (int nt = 0; nt < 4; nt++)
        acc[mt][nt] = __builtin_amdgcn_mfma_f32_16x16x32_bf16(af[mt], bf[nt], acc[mt][nt], 0, 0, 0);
  }
  int last = (l == Lo - 1);
#pragma unroll
  for (int nt = 0; nt < 2; nt++) {
    int oc = nt * 16 + r;
    float fbv = fb[layer * 32 + oc], gbv = gb[layer * 32 + oc];
#pragma unroll
    for (int mt = 0; mt < 4; mt++) {
      u16 vv[4];
#pragma unroll
      for (int rg = 0; rg < 4; rg++) {
        float f = acc[mt][nt][rg] + fbv;
        float g = acc[mt][nt + 2][rg] + gbv;
        float ft = 2.f * __builtin_amdgcn_rcpf(1.f + __expf(-2.f * f)) - 1.f;
        float sg = __builtin_amdgcn_rcpf(1.f + __expf(-g));
        vv[rg] = f2b(ft * sg);
      }
      int v0 = vbase + mt * 16 + q * 4;
      if (writehg) {
        ushort4 pk; pk.x = vv[0]; pk.y = vv[1]; pk.z = vv[2]; pk.w = vv[3];
        *(ushort4*)(hg + ((long)(b * Lo + l) * 32 + oc) * 1024 + v0) = pk;
      }
      if (last) {
#pragma unroll
        for (int rg = 0; rg < 4; rg++)
          hlast[((long)(b * 1024 + v0 + rg)) * 256 + layer * 32 + oc] = vv[rg];
      }
    }
  }
}

// ---------------- generic GEMM (m97 structure), used for adp2 + end-head ----------------
__global__ __launch_bounds__(256) void k_gemm(const u16* __restrict__ A, const u16* __restrict__ Bt,
                                              u16* __restrict__ C, int M, int N, int K,
                                              const float* __restrict__ bias, int relu) {
  __shared__ __align__(16) u16 As[128 * 32];
  __shared__ __align__(16) u16 Bs[128 * 32];
  int t = threadIdx.x, wave = t >> 6, lane = t & 63;
  int m0 = blockIdx.y * 128, n0 = blockIdx.x * 128;
  int wr = (wave >> 1) * 64, wc = (wave & 1) * 64;
  int q = lane >> 4, r = lane & 15;
  f32x4 acc[4][4] = {};
  const u16* Ag = A + (long)(m0 + wave * 32 + (lane >> 2)) * K + (lane & 3) * 8;
  const u16* Bg = Bt + (long)(n0 + wave * 32 + (lane >> 2)) * K + (lane & 3) * 8;
  u16* Al = As + wave * 1024 + lane * 8;
  u16* Bl = Bs + wave * 1024 + lane * 8;
  for (int k0 = 0; k0 < K; k0 += 32) {
    __syncthreads();
    gld_lds16(Ag + k0, Al);
    gld_lds16(Ag + 16 * K + k0, Al + 512);
    gld_lds16(Bg + k0, Bl);
    gld_lds16(Bg + 16 * K + k0, Bl + 512);
    __syncthreads();
    bf16x8 af[4], bfr[4];
#pragma unroll
    for (int i = 0; i < 4; i++) {
      af[i] = *(const bf16x8*)(As + (wr + i * 16 + r) * 32 + q * 8);
      bfr[i] = *(const bf16x8*)(Bs + (wc + i * 16 + r) * 32 + q * 8);
    }
#pragma unroll
    for (int i = 0; i < 4; i++)
#pragma unroll
      for (int j = 0; j < 4; j++)
        acc[i][j] = __builtin_amdgcn_mfma_f32_16x16x32_bf16(af[i], bfr[j], acc[i][j], 0, 0, 0);
  }
#pragma unroll
  for (int i = 0; i < 4; i++) {
    int row = m0 + wr + i * 16 + q * 4;
#pragma unroll
    for (int j = 0; j < 4; j++) {
      int col = n0 + wc + j * 16 + r;
      float bv = bias ? bias[col] : 0.f;
#pragma unroll
      for (int rg = 0; rg < 4; rg++) {
        float vv = acc[i][j][rg] + bv;
        if (relu) vv = fmaxf(vv, 0.f);
        C[(long)(row + rg) * N + col] = f2b(vv);
      }
    }
  }
}

// ---------------- FUSED: x-GEMM + gc channel-mix (mini-MFMA) + res + BN (h in v-major) ----------
// grid: x = M-blocks (fast, streams A), y = 16 n-groups (slow, B L2-resident).
// BK=64 via two half-matrices (As0/As1, Bs0/Bs1, each 128x32: row stride 64B, 2-way-free) ->
// 16 barrier iterations instead of 32. Post-loop LDS time-multiplexed as r13. Peak 33.3 KB.
#define PAD 130
__global__ __launch_bounds__(256) void k_xgc(const u16* __restrict__ hg, const u16* __restrict__ bcat,
                                             u16* __restrict__ h,
                                             const u16* __restrict__ gcwB, const float* __restrict__ gcb,
                                             const float* __restrict__ bng, const float* __restrict__ bnb,
                                             int Lo, int d, int off, int layer) {
  __shared__ __align__(16) u16 smem[16640];  // loop: As0/As1/Bs0/Bs1 4x4096; A: hgT[0,8320); B: xcs[0,16640)
  u16* As0 = smem;
  u16* As1 = smem + 4096;
  u16* Bs0 = smem + 8192;
  u16* Bs1 = smem + 12288;
  u16* hgT = smem;           // [v 0..63][m 0..127], PAD 130 (phase A)
  u16* xcs = smem;           // [n 0..127][m 0..127], PAD 130 (phase B)
  int t = threadIdx.x, wave = t >> 6, lane = t & 63;
  int m0 = blockIdx.x * 128, g = blockIdx.y, n0 = g * 128;
  int wr = (wave >> 1) * 64, wc = (wave & 1) * 64;
  int q = lane >> 4, r = lane & 15;
  const int K = 1024;
  f32x4 acc[4][4] = {};
  const u16* Ag = hg + (long)(m0 + wave * 32 + (lane >> 2)) * K + (lane & 3) * 8;
  const u16* Bg = bcat + (long)(n0 + wave * 32 + (lane >> 2)) * K + (lane & 3) * 8;
  u16* Al0 = As0 + wave * 1024 + lane * 8;
  u16* Al1 = As1 + wave * 1024 + lane * 8;
  u16* Bl0 = Bs0 + wave * 1024 + lane * 8;
  u16* Bl1 = Bs1 + wave * 1024 + lane * 8;
  for (int k0 = 0; k0 < K; k0 += 64) {
    __syncthreads();
    gld_lds16(Ag + k0, Al0);
    gld_lds16(Ag + 16 * K + k0, Al0 + 512);
    gld_lds16(Ag + k0 + 32, Al1);
    gld_lds16(Ag + 16 * K + k0 + 32, Al1 + 512);
    gld_lds16(Bg + k0, Bl0);
    gld_lds16(Bg + 16 * K + k0, Bl0 + 512);
    gld_lds16(Bg + k0 + 32, Bl1);
    gld_lds16(Bg + 16 * K + k0 + 32, Bl1 + 512);
    __syncthreads();
#pragma unroll
    for (int hh = 0; hh < 2; hh++) {
      const u16* Ah = hh ? As1 : As0;
      const u16* Bh = hh ? Bs1 : Bs0;
      bf16x8 af[4], bfr[4];
#pragma unroll
      for (int i = 0; i < 4; i++) {
        af[i] = *(const bf16x8*)(Ah + (wr + i * 16 + r) * 32 + q * 8);
        bfr[i] = *(const bf16x8*)(Bh + (wc + i * 16 + r) * 32 + q * 8);
      }
#pragma unroll
      for (int i = 0; i < 4; i++)
#pragma unroll
        for (int j = 0; j < 4; j++)
          acc[i][j] = __builtin_amdgcn_mfma_f32_16x16x32_bf16(af[i], bfr[j], acc[i][j], 0, 0, 0);
    }
  }
  __syncthreads();  // staging dead
  // phase A: stage hg tile transposed into hgT (coalesced global read)
  {
    int row = t >> 1, half = t & 1;
    const u16* src = hg + (long)(m0 + row) * K + g * 64 + half * 32;
#pragma unroll
    for (int e = 0; e < 4; e++) {
      bf16x8 v8 = *(const bf16x8*)(src + e * 8);
#pragma unroll
      for (int jj = 0; jj < 8; jj++)
        hgT[(half * 32 + e * 8 + jj) * PAD + row] = (u16)v8[jj];
    }
  }
  __syncthreads();
  bf16x8 miniA[4];
#pragma unroll
  for (int mt = 0; mt < 4; mt++)
    miniA[mt] = *(const bf16x8*)(hgT + (mt * 16 + r) * PAD + wave * 32 + q * 8);
  __syncthreads();  // hgT dead
  // phase B: acc -> xcs transposed: xcs[n_local][m_local]
#pragma unroll
  for (int i = 0; i < 4; i++) {
#pragma unroll
    for (int j = 0; j < 4; j++) {
      int row_m = wr + i * 16 + q * 4;
      int col_n = wc + j * 16 + r;
      ushort4 pk;
      pk.x = f2b(acc[i][j][0]); pk.y = f2b(acc[i][j][1]);
      pk.z = f2b(acc[i][j][2]); pk.w = f2b(acc[i][j][3]);
      *(ushort4*)(xcs + col_n * PAD + row_m) = pk;
    }
  }
  __syncthreads();
  // mini-GEMM per wave (= bl group): out[w 0..63][oc 0..31], K2=96 (hg from miniA, x1/x2 from xcs)
  int blg = blockIdx.x * 4 + wave;
  int b = blg / Lo, l = blg % Lo;
  bf16x8 bf2[2][3];
#pragma unroll
  for (int nt = 0; nt < 2; nt++)
#pragma unroll
    for (int ks = 0; ks < 3; ks++)
      bf2[nt][ks] = *(const bf16x8*)(gcwB + ((long)layer * 32 + nt * 16 + r) * 96 + ks * 32 + q * 8);
  f32x4 acc2[4][2] = {};
#pragma unroll
  for (int mt = 0; mt < 4; mt++) {
#pragma unroll
    for (int nt = 0; nt < 2; nt++)
      acc2[mt][nt] = __builtin_amdgcn_mfma_f32_16x16x32_bf16(miniA[mt], bf2[nt][0], acc2[mt][nt], 0, 0, 0);
#pragma unroll
    for (int ks = 1; ks < 3; ks++) {
      bf16x8 a2 = *(const bf16x8*)(xcs + ((ks - 1) * 64 + mt * 16 + r) * PAD + wave * 32 + q * 8);
#pragma unroll
      for (int nt = 0; nt < 2; nt++)
        acc2[mt][nt] = __builtin_amdgcn_mfma_f32_16x16x32_bf16(a2, bf2[nt][ks], acc2[mt][nt], 0, 0, 0);
    }
  }
  // epilogue: + gcb, residual, BN, in-place h write (v-major layout).
  const float rs = rsqrtf(1.f + 1e-5f);
  u16* hbase = h + ((long)(b * 13 + off + l + d) * 1024 + g * 64) * 32;
#pragma unroll
  for (int nt = 0; nt < 2; nt++) {
    int oc = nt * 16 + r;
    float gbv = gcb[layer * 32 + oc];
    float sc = bng[layer * 32 + oc] * rs;
    float bb = bnb[layer * 32 + oc];
#pragma unroll
    for (int mt = 0; mt < 4; mt++) {
#pragma unroll
      for (int rg = 0; rg < 4; rg++) {
        int w = mt * 16 + q * 4 + rg;
        u16* hp = hbase + (long)w * 32 + oc;
        float res = b2f(*hp);
        *hp = f2b((acc2[mt][nt][rg] + gbv + res) * sc + bb);
      }
    }
  }
}

// ---------------- final 12-wide conv, split-K x4 + LDS reduce: out fp32 ----------------
__global__ __launch_bounds__(256) void k_e3(const u16* __restrict__ e1, const float* __restrict__ w2,
                                            const float* __restrict__ b2, float* __restrict__ out, int b0) {
  __shared__ float red[256 * 13];
  int t = threadIdx.x;
  int r = t & 63, qq = t >> 6;
  long rowi = (long)blockIdx.x * 64 + r;
  const u16* rp = e1 + rowi * 512 + qq * 128;
  float acc[12];
#pragma unroll
  for (int o = 0; o < 12; o++) acc[o] = 0.f;
  for (int ec = 0; ec < 128; ec += 8) {
    bf16x8 raw = *(const bf16x8*)(rp + ec);
    float xv[8];
#pragma unroll
    for (int jj = 0; jj < 8; jj++) xv[jj] = b2f((u16)raw[jj]);
#pragma unroll
    for (int o = 0; o < 12; o++) {
      const float* w = w2 + o * 512 + qq * 128 + ec;
#pragma unroll
      for (int jj = 0; jj < 8; jj++) acc[o] += w[jj] * xv[jj];
    }
  }
#pragma unroll
  for (int o = 0; o < 12; o++) red[t * 13 + o] = acc[o];
  __syncthreads();
  if (t < 64) {
    long row = (long)blockIdx.x * 64 + t;
    int b = b0 + (int)(row >> 10), v = (int)(row & 1023);
#pragma unroll
    for (int o = 0; o < 12; o++) {
      float s = red[t * 13 + o] + red[(64 + t) * 13 + o] + red[(128 + t) * 13 + o] + red[(192 + t) * 13 + o];
      out[((long)b * 12 + o) * 1024 + v] = s + b2[o];
    }
  }
}

extern "C" void kernel_launch(void* const* d_in, const int* in_sizes, int n_in,
                              void* d_out, int out_size, void* d_ws, size_t ws_size,
                              hipStream_t stream) {
  const float* x = (const float*)d_in[0];
  const float* start_w = (const float*)d_in[1];
  const float* start_b = (const float*)d_in[2];
  const float* nv1 = (const float*)d_in[3];
  const float* nv2 = (const float*)d_in[4];
  const float* filter_w = (const float*)d_in[5];
  const float* filter_b = (const float*)d_in[6];
  const float* gate_w = (const float*)d_in[7];
  const float* gate_b = (const float*)d_in[8];
  const float* skip_w = (const float*)d_in[9];
  const float* skip_b = (const float*)d_in[10];
  const float* gc_w = (const float*)d_in[11];
  const float* gc_b = (const float*)d_in[12];
  const float* bn_g = (const float*)d_in[13];
  const float* bn_b = (const float*)d_in[14];
  const float* end1_w = (const float*)d_in[15];
  const float* end1_b = (const float*)d_in[16];
  const float* end2_w = (const float*)d_in[17];
  const float* end2_b = (const float*)d_in[18];
  float* out = (float*)d_out;

  char* ws = (char*)d_ws;
  // ---- fixed region ----
  u16* adp = (u16*)(ws + 0);                  //  2,097,152
  u16* bcat = (u16*)(ws + 2097152ull);        //  4,194,304 (reordered rows)
  u16* wcat = (u16*)(ws + 6291456ull);        //    131,072
  u16* e1bf = (u16*)(ws + 6422528ull);        //    262,144
  float* sbias = (float*)(ws + 6684672ull);   //      1,024
  u16* fwgB = (u16*)(ws + 6685696ull);        //     65,536
  u16* gcwB = (u16*)(ws + 6751232ull);        //     49,152
  const size_t o_dyn = 6800384ull;

  // ---- adaptive batch chunking: per-batch dyn = 2,162,688 B (h+hg+hlast) ----
  int BCH = 16;
  {
    const int cand[5] = {64, 48, 32, 24, 16};
    for (int ci = 0; ci < 5; ci++) {
      size_t need = o_dyn + (size_t)cand[ci] * 2162688ull;
      if (need <= ws_size) { BCH = cand[ci]; break; }
    }
  }
  u16* h = (u16*)(ws + o_dyn);                                 // BCH*851,968  (b,13,v,c)
  u16* hg = (u16*)(ws + o_dyn + (size_t)BCH * 851968ull);      // BCH*786,432  (b,l,c,v)
  u16* hlast = (u16*)(ws + o_dyn + (size_t)BCH * 1638400ull);  // BCH*524,288
  // pre-loop temps (in h region, dead before k_start):
  u16* adpT_p = (u16*)(ws + o_dyn);
  u16* adp2T_p = (u16*)(ws + o_dyn + 2097152ull);
  // end-phase aliases (h/hg dead then)
  u16* e1c = (u16*)(ws + o_dyn);
  u16* srelu = (u16*)(ws + o_dyn + (size_t)BCH * 1048576ull);

  static const int dilA[8] = {1, 2, 1, 2, 1, 2, 1, 2};
  static const int offA[8] = {0, 1, 3, 4, 6, 7, 9, 10};

  k_wprep<<<992, 256, 0, stream>>>(skip_w, skip_b, end1_w, filter_w, gate_w, gc_w,
                                   wcat, e1bf, sbias, fwgB, gcwB);
  k_adp<<<1024, 256, 0, stream>>>(nv1, nv2, adp);
  k_transpose<<<dim3(16, 16), 256, 0, stream>>>(adp, adpT_p);
  k_gemm<<<dim3(8, 8), 256, 0, stream>>>(adpT_p, adp, adp2T_p, 1024, 1024, 1024, nullptr, 0);
  k_pack<<<2048, 256, 0, stream>>>(adpT_p, adp2T_p, bcat);

  for (int b0 = 0; b0 < 64; b0 += BCH) {
    int bc = (64 - b0 < BCH) ? (64 - b0) : BCH;
    k_start<<<dim3(16, bc), 256, 0, stream>>>(x, start_w, start_b, h, b0);
    for (int i = 0; i < 8; i++) {
      int d = dilA[i], off = offA[i], Lo = 13 - off - d;
      k_gate<<<dim3(4, Lo, bc), 256, 0, stream>>>(h, hg, hlast, fwgB, filter_b, gate_b,
                                                  Lo, d, off, i, (i < 7) ? 1 : 0);
      if (i < 7) {
        k_xgc<<<dim3(bc * Lo / 4, 16), 256, 0, stream>>>(hg, bcat, h, gcwB, gc_b,
                                                         bn_g, bn_b, Lo, d, off, i);
      }
    }
    int Mc = bc * 1024;
    k_gemm<<<dim3(2, Mc / 128), 256, 0, stream>>>(hlast, wcat, srelu, Mc, 256, 256, sbias, 1);
    k_gemm<<<dim3(4, Mc / 128), 256, 0, stream>>>(srelu, e1bf, e1c, Mc, 512, 256, end1_b, 1);
    k_e3<<<bc * 16, 256, 0, stream>>>(e1c, end2_w, end2_b, out, b0);
  }
  (void)in_sizes; (void)n_in; (void)out_size;
}

// Round 15
// 1071.805 us; speedup vs baseline: 1.1913x; 1.0253x over previous
//
#include <hip/hip_runtime.h>

typedef unsigned short u16;
typedef unsigned int u32;
typedef __attribute__((ext_vector_type(8))) short bf16x8;
typedef __attribute__((ext_vector_type(4))) float f32x4;

__device__ __forceinline__ float b2f(u16 u) { return __uint_as_float(((u32)u) << 16); }
__device__ __forceinline__ u16 f2b(float f) {
  u32 u = __float_as_uint(f);
  return (u16)((u + 0x7FFFu + ((u >> 16) & 1u)) >> 16);
}

__device__ __forceinline__ void gld_lds16(const void* g, void* l) {
  __builtin_amdgcn_global_load_lds((const __attribute__((address_space(1))) u32*)g,
                                   (__attribute__((address_space(3))) u32*)l, 16, 0, 0);
}

// ---------------- adp = softmax(relu(nv1@nv2), axis=1), bf16, row-major (v,w) ----------------
__global__ __launch_bounds__(256) void k_adp(const float* __restrict__ nv1,
                                             const float* __restrict__ nv2,
                                             u16* __restrict__ adp) {
  int v = blockIdx.x, t = threadIdx.x;
  __shared__ float red[8];
  const float* nrow = nv1 + v * 10;
  float z[4];
#pragma unroll
  for (int j = 0; j < 4; j++) {
    int w = t + j * 256;
    float s = 0.f;
#pragma unroll
    for (int a = 0; a < 10; a++) s += nrow[a] * nv2[a * 1024 + w];
    z[j] = fmaxf(s, 0.f);
  }
  float m = fmaxf(fmaxf(z[0], z[1]), fmaxf(z[2], z[3]));
  for (int off = 32; off; off >>= 1) m = fmaxf(m, __shfl_down(m, off));
  if ((t & 63) == 0) red[t >> 6] = m;
  __syncthreads();
  m = fmaxf(fmaxf(red[0], red[1]), fmaxf(red[2], red[3]));
  float e[4], s = 0.f;
#pragma unroll
  for (int j = 0; j < 4; j++) { e[j] = __expf(z[j] - m); s += e[j]; }
  for (int off = 32; off; off >>= 1) s += __shfl_down(s, off);
  if ((t & 63) == 0) red[4 + (t >> 6)] = s;
  __syncthreads();
  s = red[4] + red[5] + red[6] + red[7];
  float inv = 1.0f / s;
#pragma unroll
  for (int j = 0; j < 4; j++) adp[(long)v * 1024 + t + j * 256] = f2b(e[j] * inv);
}

// ---------------- transpose 1024x1024 bf16 ----------------
__global__ __launch_bounds__(256) void k_transpose(const u16* __restrict__ in, u16* __restrict__ out) {
  __shared__ u16 tile[64 * 65];
  int w0 = blockIdx.x * 64, v0 = blockIdx.y * 64, t = threadIdx.x;
  int c = t & 63, r4 = t >> 6;
  for (int rr = r4; rr < 64; rr += 4) tile[rr * 65 + c] = in[(long)(v0 + rr) * 1024 + w0 + c];
  __syncthreads();
  for (int rr = r4; rr < 64; rr += 4) out[(long)(w0 + rr) * 1024 + v0 + c] = tile[c * 65 + rr];
}

// ---------------- pack bcat rows: n = (v>>6)*128 + src*64 + (v&63) ----------------
__global__ __launch_bounds__(256) void k_pack(const u16* __restrict__ adpT, const u16* __restrict__ adp2T,
                                              u16* __restrict__ bcat) {
  int n = blockIdx.x;
  int g = n >> 7, rem = n & 127, src = rem >> 6, v = g * 64 + (rem & 63);
  const u16* s = (src ? adp2T : adpT) + (long)v * 1024;
  u16* d = bcat + (long)n * 1024;
  ((ushort4*)d)[threadIdx.x] = ((const ushort4*)s)[threadIdx.x];
}

// ---------------- weight repacks + summed skip bias ----------------
// fwgB[layer][n 0..63][k 0..63] bf16: n<32 -> filter oc, n>=32 -> gate oc; k = tap*32 + ci.
__global__ __launch_bounds__(256) void k_wprep(const float* __restrict__ skw, const float* __restrict__ skb,
                                               const float* __restrict__ e1w,
                                               const float* __restrict__ fw, const float* __restrict__ gw,
                                               const float* __restrict__ gcw,
                                               u16* __restrict__ wcat, u16* __restrict__ e1bf,
                                               float* __restrict__ sbias,
                                               u16* __restrict__ fwgB, u16* __restrict__ gcwB) {
  int idx = blockIdx.x * 256 + threadIdx.x;
  if (idx < 65536) {
    int cp = idx >> 8, k = idx & 255, i = k >> 5, c = k & 31;
    wcat[idx] = f2b(skw[(i * 256 + cp) * 32 + c]);
  } else if (idx < 196608) {
    int j = idx - 65536;
    e1bf[j] = f2b(e1w[j]);
  } else if (idx < 229376) {
    int j = idx - 196608;
    int layer = j >> 12, rem = j & 4095, n = rem >> 6, k = rem & 63;
    int tap = k >> 5, ci = k & 31, oc = n & 31;
    const float* src = (n < 32) ? fw : gw;
    fwgB[j] = f2b(src[((layer * 32 + oc) * 32 + ci) * 2 + tap]);
  } else if (idx < 253952) {
    int j = idx - 229376;  // native-order bf16 copy of gc_w
    gcwB[j] = f2b(gcw[j]);
  }
  if (idx < 256) {
    float s = 0.f;
    for (int i = 0; i < 8; i++) s += skb[i * 256 + idx];
    sbias[idx] = s;
  }
}

// ---------------- start conv: h[b][slot][v][c] bf16 — full-line (64B) writes per thread --------
__global__ __launch_bounds__(256) void k_start(const float* __restrict__ x, const float* __restrict__ sw,
                                               const float* __restrict__ sb, u16* __restrict__ h, int b0) {
  int bl = blockIdx.y, bg = b0 + bl, v0 = blockIdx.x * 64, t = threadIdx.x;
  __shared__ float xs[2 * 832];  // [i][vl*13+l]
  for (int idx = t; idx < 2 * 832; idx += 256) {
    int i = idx / 832, rem = idx % 832;
    xs[idx] = x[((long)(bg * 2 + i) * 1024 + v0) * 13 + rem];
  }
  __syncthreads();
  for (int p = t; p < 832; p += 256) {
    int l = p % 13, vl = p / 13;
    float x0 = xs[vl * 13 + l];
    float x1 = xs[832 + vl * 13 + l];
    u16* dst = h + ((long)(bl * 13 + l) * 1024 + v0 + vl) * 32;
#pragma unroll
    for (int cq = 0; cq < 4; cq++) {
      bf16x8 pk;
#pragma unroll
      for (int j = 0; j < 8; j++) {
        int c = cq * 8 + j;
        pk[j] = (short)f2b(sw[c * 2 + 0] * x0 + sw[c * 2 + 1] * x1 + sb[c]);
      }
      *(bf16x8*)(dst + cq * 8) = pk;
    }
  }
}

// ---------------- gated dilated conv via MFMA: M=v, N=64 (f|g), K=64 (2 taps x 32 ci) ----------
__global__ __launch_bounds__(256, 2) void k_gate(const u16* __restrict__ h, u16* __restrict__ hg,
                                                 u16* __restrict__ hlast,
                                                 const u16* __restrict__ fwgB,
                                                 const float* __restrict__ fb, const float* __restrict__ gb,
                                                 int Lo, int d, int off, int layer, int writehg) {
  int t = threadIdx.x, wave = t >> 6, lane = t & 63;
  int q = lane >> 4, r = lane & 15;
  int b = blockIdx.z, l = blockIdx.y;
  int vbase = blockIdx.x * 256 + wave * 64;
  f32x4 acc[4][4] = {};
  const u16* wb = fwgB + layer * 4096;
#pragma unroll
  for (int ks = 0; ks < 2; ks++) {
    const u16* hrow = h + ((long)(b * 13 + off + l + ks * d) * 1024) * 32;
    bf16x8 af[4], bf[4];
#pragma unroll
    for (int mt = 0; mt < 4; mt++)
      af[mt] = *(const bf16x8*)(hrow + (long)(vbase + mt * 16 + r) * 32 + q * 8);
#pragma unroll
    for (int nt = 0; nt < 4; nt++)
      bf[nt] = *(const bf16x8*)(wb + (nt * 16 + r) * 64 + ks * 32 + q * 8);
#pragma unroll
    for (int mt = 0; mt < 4; mt++)
#pragma unroll
      for (int nt = 0; nt < 4; nt++)
        acc[mt][nt] = __builtin_amdgcn_mfma_f32_16x16x32_bf16(af[mt], bf[nt], acc[mt][nt], 0, 0, 0);
  }
  int last = (l == Lo - 1);
#pragma unroll
  for (int nt = 0; nt < 2; nt++) {
    int oc = nt * 16 + r;
    float fbv = fb[layer * 32 + oc], gbv = gb[layer * 32 + oc];
#pragma unroll
    for (int mt = 0; mt < 4; mt++) {
      u16 vv[4];
#pragma unroll
      for (int rg = 0; rg < 4; rg++) {
        float f = acc[mt][nt][rg] + fbv;
        float g = acc[mt][nt + 2][rg] + gbv;
        float ft = 2.f * __builtin_amdgcn_rcpf(1.f + __expf(-2.f * f)) - 1.f;
        float sg = __builtin_amdgcn_rcpf(1.f + __expf(-g));
        vv[rg] = f2b(ft * sg);
      }
      int v0 = vbase + mt * 16 + q * 4;
      if (writehg) {
        ushort4 pk; pk.x = vv[0]; pk.y = vv[1]; pk.z = vv[2]; pk.w = vv[3];
        *(ushort4*)(hg + ((long)(b * Lo + l) * 32 + oc) * 1024 + v0) = pk;
      }
      if (last) {
#pragma unroll
        for (int rg = 0; rg < 4; rg++)
          hlast[((long)(b * 1024 + v0 + rg)) * 256 + layer * 32 + oc] = vv[rg];
      }
    }
  }
}

// ---------------- generic GEMM (m97 structure), used for adp2 + end-head ----------------
__global__ __launch_bounds__(256) void k_gemm(const u16* __restrict__ A, const u16* __restrict__ Bt,
                                              u16* __restrict__ C, int M, int N, int K,
                                              const float* __restrict__ bias, int relu) {
  __shared__ __align__(16) u16 As[128 * 32];
  __shared__ __align__(16) u16 Bs[128 * 32];
  int t = threadIdx.x, wave = t >> 6, lane = t & 63;
  int m0 = blockIdx.y * 128, n0 = blockIdx.x * 128;
  int wr = (wave >> 1) * 64, wc = (wave & 1) * 64;
  int q = lane >> 4, r = lane & 15;
  f32x4 acc[4][4] = {};
  const u16* Ag = A + (long)(m0 + wave * 32 + (lane >> 2)) * K + (lane & 3) * 8;
  const u16* Bg = Bt + (long)(n0 + wave * 32 + (lane >> 2)) * K + (lane & 3) * 8;
  u16* Al = As + wave * 1024 + lane * 8;
  u16* Bl = Bs + wave * 1024 + lane * 8;
  for (int k0 = 0; k0 < K; k0 += 32) {
    __syncthreads();
    gld_lds16(Ag + k0, Al);
    gld_lds16(Ag + 16 * K + k0, Al + 512);
    gld_lds16(Bg + k0, Bl);
    gld_lds16(Bg + 16 * K + k0, Bl + 512);
    __syncthreads();
    bf16x8 af[4], bfr[4];
#pragma unroll
    for (int i = 0; i < 4; i++) {
      af[i] = *(const bf16x8*)(As + (wr + i * 16 + r) * 32 + q * 8);
      bfr[i] = *(const bf16x8*)(Bs + (wc + i * 16 + r) * 32 + q * 8);
    }
#pragma unroll
    for (int i = 0; i < 4; i++)
#pragma unroll
      for (int j = 0; j < 4; j++)
        acc[i][j] = __builtin_amdgcn_mfma_f32_16x16x32_bf16(af[i], bfr[j], acc[i][j], 0, 0, 0);
  }
#pragma unroll
  for (int i = 0; i < 4; i++) {
    int row = m0 + wr + i * 16 + q * 4;
#pragma unroll
    for (int j = 0; j < 4; j++) {
      int col = n0 + wc + j * 16 + r;
      float bv = bias ? bias[col] : 0.f;
#pragma unroll
      for (int rg = 0; rg < 4; rg++) {
        float vv = acc[i][j][rg] + bv;
        if (relu) vv = fmaxf(vv, 0.f);
        C[(long)(row + rg) * N + col] = f2b(vv);
      }
    }
  }
}

// ---------------- FUSED: x-GEMM + gc channel-mix (mini-MFMA) + res + BN (h in v-major) ----------
// L2-blocked dispatch swizzle: linear block ID -> (super-tile of 16 m-blocks, g, mi) so a 4 MB
// A super-tile is reused by all 16 n-groups while L2-resident (A HBM-fetched once, not 16x).
// K-loop = r13 BK=32 (measured best). Post-loop LDS time-multiplexed. Peak 33.3 KB.
#define PAD 130
__global__ __launch_bounds__(256) void k_xgc(const u16* __restrict__ hg, const u16* __restrict__ bcat,
                                             u16* __restrict__ h,
                                             const u16* __restrict__ gcwB, const float* __restrict__ gcb,
                                             const float* __restrict__ bng, const float* __restrict__ bnb,
                                             int Lo, int d, int off, int layer) {
  __shared__ __align__(16) u16 smem[16640];  // loop: As[0,4096) Bs[4096,8192); A: hgT[0,8320); B: xcs[0,16640)
  u16* As = smem;
  u16* Bs = smem + 4096;
  u16* hgT = smem;           // [v 0..63][m 0..127], PAD 130 (phase A)
  u16* xcs = smem;           // [n 0..127][m 0..127], PAD 130 (phase B)
  int t = threadIdx.x, wave = t >> 6, lane = t & 63;
  // ---- block-ID remap for L2 A-reuse ----
  int X = gridDim.x;  // m-blocks (multiple of 16 when BCH=64)
  int mblk, g;
  if ((X & 15) == 0) {
    int lin = blockIdx.x + X * blockIdx.y;
    int mi = lin & 15, gg = (lin >> 4) & 15, stile = lin >> 8;
    mblk = stile * 16 + mi;
    g = gg;
  } else {
    mblk = blockIdx.x;
    g = blockIdx.y;
  }
  int m0 = mblk * 128, n0 = g * 128;
  int wr = (wave >> 1) * 64, wc = (wave & 1) * 64;
  int q = lane >> 4, r = lane & 15;
  const int K = 1024;
  f32x4 acc[4][4] = {};
  const u16* Ag = hg + (long)(m0 + wave * 32 + (lane >> 2)) * K + (lane & 3) * 8;
  const u16* Bg = bcat + (long)(n0 + wave * 32 + (lane >> 2)) * K + (lane & 3) * 8;
  u16* Al = As + wave * 1024 + lane * 8;
  u16* Bl = Bs + wave * 1024 + lane * 8;
  for (int k0 = 0; k0 < K; k0 += 32) {
    __syncthreads();
    gld_lds16(Ag + k0, Al);
    gld_lds16(Ag + 16 * K + k0, Al + 512);
    gld_lds16(Bg + k0, Bl);
    gld_lds16(Bg + 16 * K + k0, Bl + 512);
    __syncthreads();
    bf16x8 af[4], bfr[4];
#pragma unroll
    for (int i = 0; i < 4; i++) {
      af[i] = *(const bf16x8*)(As + (wr + i * 16 + r) * 32 + q * 8);
      bfr[i] = *(const bf16x8*)(Bs + (wc + i * 16 + r) * 32 + q * 8);
    }
#pragma unroll
    for (int i = 0; i < 4; i++)
#pragma unroll
      for (int j = 0; j < 4; j++)
        acc[i][j] = __builtin_amdgcn_mfma_f32_16x16x32_bf16(af[i], bfr[j], acc[i][j], 0, 0, 0);
  }
  __syncthreads();  // As/Bs dead
  // phase A: stage hg tile transposed into hgT (coalesced global read)
  {
    int row = t >> 1, half = t & 1;
    const u16* src = hg + (long)(m0 + row) * K + g * 64 + half * 32;
#pragma unroll
    for (int e = 0; e < 4; e++) {
      bf16x8 v8 = *(const bf16x8*)(src + e * 8);
#pragma unroll
      for (int jj = 0; jj < 8; jj++)
        hgT[(half * 32 + e * 8 + jj) * PAD + row] = (u16)v8[jj];
    }
  }
  __syncthreads();
  bf16x8 miniA[4];
#pragma unroll
  for (int mt = 0; mt < 4; mt++)
    miniA[mt] = *(const bf16x8*)(hgT + (mt * 16 + r) * PAD + wave * 32 + q * 8);
  __syncthreads();  // hgT dead
  // phase B: acc -> xcs transposed: xcs[n_local][m_local]
#pragma unroll
  for (int i = 0; i < 4; i++) {
#pragma unroll
    for (int j = 0; j < 4; j++) {
      int row_m = wr + i * 16 + q * 4;
      int col_n = wc + j * 16 + r;
      ushort4 pk;
      pk.x = f2b(acc[i][j][0]); pk.y = f2b(acc[i][j][1]);
      pk.z = f2b(acc[i][j][2]); pk.w = f2b(acc[i][j][3]);
      *(ushort4*)(xcs + col_n * PAD + row_m) = pk;
    }
  }
  __syncthreads();
  // mini-GEMM per wave (= bl group): out[w 0..63][oc 0..31], K2=96 (hg from miniA, x1/x2 from xcs)
  int blg = mblk * 4 + wave;
  int b = blg / Lo, l = blg % Lo;
  bf16x8 bf2[2][3];
#pragma unroll
  for (int nt = 0; nt < 2; nt++)
#pragma unroll
    for (int ks = 0; ks < 3; ks++)
      bf2[nt][ks] = *(const bf16x8*)(gcwB + ((long)layer * 32 + nt * 16 + r) * 96 + ks * 32 + q * 8);
  f32x4 acc2[4][2] = {};
#pragma unroll
  for (int mt = 0; mt < 4; mt++) {
#pragma unroll
    for (int nt = 0; nt < 2; nt++)
      acc2[mt][nt] = __builtin_amdgcn_mfma_f32_16x16x32_bf16(miniA[mt], bf2[nt][0], acc2[mt][nt], 0, 0, 0);
#pragma unroll
    for (int ks = 1; ks < 3; ks++) {
      bf16x8 a2 = *(const bf16x8*)(xcs + ((ks - 1) * 64 + mt * 16 + r) * PAD + wave * 32 + q * 8);
#pragma unroll
      for (int nt = 0; nt < 2; nt++)
        acc2[mt][nt] = __builtin_amdgcn_mfma_f32_16x16x32_bf16(a2, bf2[nt][ks], acc2[mt][nt], 0, 0, 0);
    }
  }
  // epilogue: + gcb, residual, BN, in-place h write (v-major layout).
  const float rs = rsqrtf(1.f + 1e-5f);
  u16* hbase = h + ((long)(b * 13 + off + l + d) * 1024 + g * 64) * 32;
#pragma unroll
  for (int nt = 0; nt < 2; nt++) {
    int oc = nt * 16 + r;
    float gbv = gcb[layer * 32 + oc];
    float sc = bng[layer * 32 + oc] * rs;
    float bb = bnb[layer * 32 + oc];
#pragma unroll
    for (int mt = 0; mt < 4; mt++) {
#pragma unroll
      for (int rg = 0; rg < 4; rg++) {
        int w = mt * 16 + q * 4 + rg;
        u16* hp = hbase + (long)w * 32 + oc;
        float res = b2f(*hp);
        *hp = f2b((acc2[mt][nt][rg] + gbv + res) * sc + bb);
      }
    }
  }
}

// ---------------- final 12-wide conv, split-K x4 + LDS reduce: out fp32 ----------------
__global__ __launch_bounds__(256) void k_e3(const u16* __restrict__ e1, const float* __restrict__ w2,
                                            const float* __restrict__ b2, float* __restrict__ out, int b0) {
  __shared__ float red[256 * 13];
  int t = threadIdx.x;
  int r = t & 63, qq = t >> 6;
  long rowi = (long)blockIdx.x * 64 + r;
  const u16* rp = e1 + rowi * 512 + qq * 128;
  float acc[12];
#pragma unroll
  for (int o = 0; o < 12; o++) acc[o] = 0.f;
  for (int ec = 0; ec < 128; ec += 8) {
    bf16x8 raw = *(const bf16x8*)(rp + ec);
    float xv[8];
#pragma unroll
    for (int jj = 0; jj < 8; jj++) xv[jj] = b2f((u16)raw[jj]);
#pragma unroll
    for (int o = 0; o < 12; o++) {
      const float* w = w2 + o * 512 + qq * 128 + ec;
#pragma unroll
      for (int jj = 0; jj < 8; jj++) acc[o] += w[jj] * xv[jj];
    }
  }
#pragma unroll
  for (int o = 0; o < 12; o++) red[t * 13 + o] = acc[o];
  __syncthreads();
  if (t < 64) {
    long row = (long)blockIdx.x * 64 + t;
    int b = b0 + (int)(row >> 10), v = (int)(row & 1023);
#pragma unroll
    for (int o = 0; o < 12; o++) {
      float s = red[t * 13 + o] + red[(64 + t) * 13 + o] + red[(128 + t) * 13 + o] + red[(192 + t) * 13 + o];
      out[((long)b * 12 + o) * 1024 + v] = s + b2[o];
    }
  }
}

extern "C" void kernel_launch(void* const* d_in, const int* in_sizes, int n_in,
                              void* d_out, int out_size, void* d_ws, size_t ws_size,
                              hipStream_t stream) {
  const float* x = (const float*)d_in[0];
  const float* start_w = (const float*)d_in[1];
  const float* start_b = (const float*)d_in[2];
  const float* nv1 = (const float*)d_in[3];
  const float* nv2 = (const float*)d_in[4];
  const float* filter_w = (const float*)d_in[5];
  const float* filter_b = (const float*)d_in[6];
  const float* gate_w = (const float*)d_in[7];
  const float* gate_b = (const float*)d_in[8];
  const float* skip_w = (const float*)d_in[9];
  const float* skip_b = (const float*)d_in[10];
  const float* gc_w = (const float*)d_in[11];
  const float* gc_b = (const float*)d_in[12];
  const float* bn_g = (const float*)d_in[13];
  const float* bn_b = (const float*)d_in[14];
  const float* end1_w = (const float*)d_in[15];
  const float* end1_b = (const float*)d_in[16];
  const float* end2_w = (const float*)d_in[17];
  const float* end2_b = (const float*)d_in[18];
  float* out = (float*)d_out;

  char* ws = (char*)d_ws;
  // ---- fixed region ----
  u16* adp = (u16*)(ws + 0);                  //  2,097,152
  u16* bcat = (u16*)(ws + 2097152ull);        //  4,194,304 (reordered rows)
  u16* wcat = (u16*)(ws + 6291456ull);        //    131,072
  u16* e1bf = (u16*)(ws + 6422528ull);        //    262,144
  float* sbias = (float*)(ws + 6684672ull);   //      1,024
  u16* fwgB = (u16*)(ws + 6685696ull);        //     65,536
  u16* gcwB = (u16*)(ws + 6751232ull);        //     49,152
  const size_t o_dyn = 6800384ull;

  // ---- adaptive batch chunking: per-batch dyn = 2,162,688 B (h+hg+hlast) ----
  int BCH = 16;
  {
    const int cand[5] = {64, 48, 32, 24, 16};
    for (int ci = 0; ci < 5; ci++) {
      size_t need = o_dyn + (size_t)cand[ci] * 2162688ull;
      if (need <= ws_size) { BCH = cand[ci]; break; }
    }
  }
  u16* h = (u16*)(ws + o_dyn);                                 // BCH*851,968  (b,13,v,c)
  u16* hg = (u16*)(ws + o_dyn + (size_t)BCH * 851968ull);      // BCH*786,432  (b,l,c,v)
  u16* hlast = (u16*)(ws + o_dyn + (size_t)BCH * 1638400ull);  // BCH*524,288
  // pre-loop temps (in h region, dead before k_start):
  u16* adpT_p = (u16*)(ws + o_dyn);
  u16* adp2T_p = (u16*)(ws + o_dyn + 2097152ull);
  // end-phase aliases (h/hg dead then)
  u16* e1c = (u16*)(ws + o_dyn);
  u16* srelu = (u16*)(ws + o_dyn + (size_t)BCH * 1048576ull);

  static const int dilA[8] = {1, 2, 1, 2, 1, 2, 1, 2};
  static const int offA[8] = {0, 1, 3, 4, 6, 7, 9, 10};

  k_wprep<<<992, 256, 0, stream>>>(skip_w, skip_b, end1_w, filter_w, gate_w, gc_w,
                                   wcat, e1bf, sbias, fwgB, gcwB);
  k_adp<<<1024, 256, 0, stream>>>(nv1, nv2, adp);
  k_transpose<<<dim3(16, 16), 256, 0, stream>>>(adp, adpT_p);
  k_gemm<<<dim3(8, 8), 256, 0, stream>>>(adpT_p, adp, adp2T_p, 1024, 1024, 1024, nullptr, 0);
  k_pack<<<2048, 256, 0, stream>>>(adpT_p, adp2T_p, bcat);

  for (int b0 = 0; b0 < 64; b0 += BCH) {
    int bc = (64 - b0 < BCH) ? (64 - b0) : BCH;
    k_start<<<dim3(16, bc), 256, 0, stream>>>(x, start_w, start_b, h, b0);
    for (int i = 0; i < 8; i++) {
      int d = dilA[i], off = offA[i], Lo = 13 - off - d;
      k_gate<<<dim3(4, Lo, bc), 256, 0, stream>>>(h, hg, hlast, fwgB, filter_b, gate_b,
                                                  Lo, d, off, i, (i < 7) ? 1 : 0);
      if (i < 7) {
        k_xgc<<<dim3(bc * Lo / 4, 16), 256, 0, stream>>>(hg, bcat, h, gcwB, gc_b,
                                                         bn_g, bn_b, Lo, d, off, i);
      }
    }
    int Mc = bc * 1024;
    k_gemm<<<dim3(2, Mc / 128), 256, 0, stream>>>(hlast, wcat, srelu, Mc, 256, 256, sbias, 1);
    k_gemm<<<dim3(4, Mc / 128), 256, 0, stream>>>(srelu, e1bf, e1c, Mc, 512, 256, end1_b, 1);
    k_e3<<<bc * 16, 256, 0, stream>>>(e1c, end2_w, end2_b, out, b0);
  }
  (void)in_sizes; (void)n_in; (void)out_size;
}